// Round 1
// baseline (1286.849 us; speedup 1.0000x reference)
//
#include <hip/hip_runtime.h>
#include <hip/hip_bf16.h>
#include <cstddef>

#define P_   2048
#define B_   16
#define E_   1024
#define DIN_ 128
#define D_   128
#define L_   16
#define TD_  384   // 3*D

// ---------------- pt table: pt[p][t] = path id, or -1 for padding ----------
__global__ void k_pt_init(int* __restrict__ pt) {
    int i = blockIdx.x * 256 + threadIdx.x;
    if (i < P_ * L_) pt[i] = -1;
}

__global__ void k_pt_scatter(const int* __restrict__ paths, const int* __restrict__ idx,
                             const int* __restrict__ seqs, int J, int* __restrict__ pt) {
    int j = blockIdx.x * 256 + threadIdx.x;
    if (j < J) pt[idx[j] * L_ + seqs[j]] = paths[j];
}

// ---------------- M = wq @ wk^T  (M[j][d] = sum_k wq[j][k] * wk[d][k]) -----
__global__ __launch_bounds__(128) void k_M(const float* __restrict__ wq,
                                           const float* __restrict__ wk,
                                           float* __restrict__ M) {
    __shared__ float wk_lds[128 * 129];   // padded: bank = (d+k)%32, conflict-free
    __shared__ float wq_row[128];
    int d = threadIdx.x;
    int j = blockIdx.x;
    wq_row[d] = wq[j * 128 + d];
    for (int r = 0; r < 128; ++r) wk_lds[r * 129 + d] = wk[r * 128 + d];
    __syncthreads();
    float acc = 0.f;
    for (int k = 0; k < 128; ++k) acc += wq_row[k] * wk_lds[d * 129 + k];
    M[j * 128 + d] = acc;
}

// ---------------- G[b*E+e][c] = inputs[b,e,:] @ W_in[:,c] + b_in[c] --------
__global__ __launch_bounds__(384) void k_G(const float* __restrict__ inputs,
                                           const float* __restrict__ W_in,
                                           const float* __restrict__ b_in,
                                           float* __restrict__ G) {
    __shared__ __align__(16) float in_lds[16][128];
    int c = threadIdx.x;                 // 0..383
    int row0 = blockIdx.x * 16;          // 1024 blocks over 16384 rows
    for (int i = c; i < 16 * 128; i += 384)
        in_lds[i >> 7][i & 127] = inputs[row0 * 128 + i];
    __syncthreads();
    float acc[16];
#pragma unroll
    for (int r = 0; r < 16; ++r) acc[r] = 0.f;
    for (int k = 0; k < 128; k += 4) {
        float w0 = W_in[(k + 0) * TD_ + c];
        float w1 = W_in[(k + 1) * TD_ + c];
        float w2 = W_in[(k + 2) * TD_ + c];
        float w3 = W_in[(k + 3) * TD_ + c];
#pragma unroll
        for (int r = 0; r < 16; ++r) {
            float4 h4 = *(const float4*)&in_lds[r][k];
            acc[r] += h4.x * w0 + h4.y * w1 + h4.z * w2 + h4.w * w3;
        }
    }
    float b = b_in[c];
#pragma unroll
    for (int r = 0; r < 16; ++r) G[(size_t)(row0 + r) * TD_ + c] = acc[r] + b;
}

// ---------------- GRU recurrence, 16 seqs per block ------------------------
// thread d owns gate columns (d, 128+d, 256+d): gates computed fully in-register.
__global__ __launch_bounds__(128) void k_rec(const float* __restrict__ W_rec,
                                             const float* __restrict__ b_rec,
                                             const float* __restrict__ b_in,
                                             const float* __restrict__ G,
                                             const int* __restrict__ pt,
                                             __hip_bfloat16* __restrict__ hs) {
    __shared__ __align__(16) float h_lds[16][128];
    __shared__ int pt_lds[16][16];
    int d = threadIdx.x;
    int n0 = blockIdx.x * 16;
    int b = n0 >> 11;            // n0 / P_
    int p0 = n0 & (P_ - 1);

    for (int i = d; i < 16 * 16; i += 128)
        pt_lds[i >> 4][i & 15] = pt[p0 * L_ + i];
#pragma unroll
    for (int r = 0; r < 16; ++r) h_lds[r][d] = 0.f;

    float bz = b_in[d], br = b_in[128 + d], bh = b_in[256 + d];
    float rz = b_rec[d], rr = b_rec[128 + d], rh = b_rec[256 + d];
    __syncthreads();

    for (int t = 0; t < L_; ++t) {
        float az[16], ar[16], ah[16];
#pragma unroll
        for (int r = 0; r < 16; ++r) { az[r] = 0.f; ar[r] = 0.f; ah[r] = 0.f; }

        for (int k = 0; k < 128; k += 4) {
            const float* wp = W_rec + (size_t)k * TD_ + d;
            float wz0 = wp[0 * TD_], wr0 = wp[0 * TD_ + 128], wh0 = wp[0 * TD_ + 256];
            float wz1 = wp[1 * TD_], wr1 = wp[1 * TD_ + 128], wh1 = wp[1 * TD_ + 256];
            float wz2 = wp[2 * TD_], wr2 = wp[2 * TD_ + 128], wh2 = wp[2 * TD_ + 256];
            float wz3 = wp[3 * TD_], wr3 = wp[3 * TD_ + 128], wh3 = wp[3 * TD_ + 256];
#pragma unroll
            for (int r = 0; r < 16; ++r) {
                float4 h4 = *(const float4*)&h_lds[r][k];
                az[r] += h4.x * wz0 + h4.y * wz1 + h4.z * wz2 + h4.w * wz3;
                ar[r] += h4.x * wr0 + h4.y * wr1 + h4.z * wr2 + h4.w * wr3;
                ah[r] += h4.x * wh0 + h4.y * wh1 + h4.z * wh2 + h4.w * wh3;
            }
        }
        __syncthreads();   // all waves done reading old h
#pragma unroll
        for (int r = 0; r < 16; ++r) {
            int e = pt_lds[r][t];
            float xz, xr, xh;
            if (e >= 0) {
                const float* g = G + (size_t)(b * E_ + e) * TD_;
                xz = g[d]; xr = g[128 + d]; xh = g[256 + d];
            } else {
                xz = bz; xr = br; xh = bh;
            }
            float hz = az[r] + rz, hr = ar[r] + rr, hh = ah[r] + rh;
            float z  = 1.f / (1.f + __expf(-(xz + hz)));
            float rg = 1.f / (1.f + __expf(-(xr + hr)));
            float pre = xh + rg * hh;
            // overflow-safe tanh
            float t2 = __expf(-2.f * fabsf(pre));
            float th = (1.f - t2) / (1.f + t2);
            float hc = (pre >= 0.f) ? th : -th;
            float hp = h_lds[r][d];
            float hn = z * hp + (1.f - z) * hc;
            h_lds[r][d] = hn;   // each thread touches only its own [r][d]
            hs[((size_t)(n0 + r) * L_ + t) * D_ + d] = __float2bfloat16(hn);
        }
        __syncthreads();   // h writes visible before next k-loop
    }
}

// ---------------- attention: qk = last@M; att_l = hs_l.qk; ctx = (sum att*hs)@wv
__global__ __launch_bounds__(128) void k_att(const __hip_bfloat16* __restrict__ hs,
                                             const float* __restrict__ M,
                                             const float* __restrict__ wv,
                                             float* __restrict__ out) {
    __shared__ float last_lds[4][128];
    __shared__ float s_lds[4][128];
    __shared__ float red[8];
    int d = threadIdx.x;
    int n0 = blockIdx.x * 4;
    int wave = d >> 6, lane = d & 63;

#pragma unroll
    for (int r = 0; r < 4; ++r)
        last_lds[r][d] = __bfloat162float(hs[((size_t)(n0 + r) * L_ + 15) * D_ + d]);
    __syncthreads();

    float qk[4] = {0.f, 0.f, 0.f, 0.f};
    for (int k = 0; k < 128; ++k) {
        float mv = M[k * 128 + d];
#pragma unroll
        for (int r = 0; r < 4; ++r) qk[r] += last_lds[r][k] * mv;
    }

    float s[4] = {0.f, 0.f, 0.f, 0.f};
    for (int l = 0; l < L_; ++l) {
        float hv[4], p[4];
#pragma unroll
        for (int r = 0; r < 4; ++r) {
            hv[r] = __bfloat162float(hs[((size_t)(n0 + r) * L_ + l) * D_ + d]);
            p[r] = hv[r] * qk[r];
        }
#pragma unroll
        for (int r = 0; r < 4; ++r) {
            float v = p[r];
            for (int o = 32; o > 0; o >>= 1) v += __shfl_down(v, o, 64);
            if (lane == 0) red[wave * 4 + r] = v;
        }
        __syncthreads();
#pragma unroll
        for (int r = 0; r < 4; ++r) {
            float att = red[r] + red[4 + r];
            s[r] += att * hv[r];
        }
        __syncthreads();
    }

#pragma unroll
    for (int r = 0; r < 4; ++r) s_lds[r][d] = s[r];
    __syncthreads();
    float c4[4] = {0.f, 0.f, 0.f, 0.f};
    for (int k = 0; k < 128; ++k) {
        float wvv = wv[k * 128 + d];
#pragma unroll
        for (int r = 0; r < 4; ++r) c4[r] += s_lds[r][k] * wvv;
    }
#pragma unroll
    for (int r = 0; r < 4; ++r) out[(size_t)(n0 + r) * D_ + d] = c4[r];
}

// ---------------------------------------------------------------------------
extern "C" void kernel_launch(void* const* d_in, const int* in_sizes, int n_in,
                              void* d_out, int out_size, void* d_ws, size_t ws_size,
                              hipStream_t stream) {
    const float* inputs = (const float*)d_in[0];
    const float* W_in   = (const float*)d_in[1];
    const float* W_rec  = (const float*)d_in[2];
    const float* b_in   = (const float*)d_in[3];
    const float* b_rec  = (const float*)d_in[4];
    const float* wq     = (const float*)d_in[5];
    const float* wk     = (const float*)d_in[6];
    const float* wv     = (const float*)d_in[7];
    const int* paths    = (const int*)d_in[8];
    const int* idx      = (const int*)d_in[9];
    const int* seqs     = (const int*)d_in[10];
    int J = in_sizes[8];

    // workspace layout
    const size_t off_pt = 0;
    const size_t off_M  = off_pt + (size_t)P_ * L_ * sizeof(int);           // 131072
    const size_t off_G  = off_M + 128 * 128 * sizeof(float);                // +65536
    const size_t off_hs = off_G + (size_t)B_ * E_ * TD_ * sizeof(float);    // +25165824
    // hs: N*L*D bf16 = 134217728 bytes; total ~152.2 MB
    char* ws = (char*)d_ws;
    int*   pt = (int*)(ws + off_pt);
    float* M  = (float*)(ws + off_M);
    float* G  = (float*)(ws + off_G);
    __hip_bfloat16* hs = (__hip_bfloat16*)(ws + off_hs);
    float* out = (float*)d_out;

    k_pt_init<<<dim3((P_ * L_ + 255) / 256), dim3(256), 0, stream>>>(pt);
    k_pt_scatter<<<dim3((J + 255) / 256), dim3(256), 0, stream>>>(paths, idx, seqs, J, pt);
    k_M<<<dim3(128), dim3(128), 0, stream>>>(wq, wk, M);
    k_G<<<dim3(B_ * E_ / 16), dim3(384), 0, stream>>>(inputs, W_in, b_in, G);
    k_rec<<<dim3(B_ * P_ / 16), dim3(128), 0, stream>>>(W_rec, b_rec, b_in, G, pt, hs);
    k_att<<<dim3(B_ * P_ / 4), dim3(128), 0, stream>>>(hs, M, wv, out);
}

// Round 3
// 504.529 us; speedup vs baseline: 2.5506x; 2.5506x over previous
//
#include <hip/hip_runtime.h>
#include <hip/hip_bf16.h>
#include <cstddef>

#define P_   2048
#define B_   16
#define E_   1024
#define DIN_ 128
#define D_   128
#define L_   16
#define TD_  384   // 3*D
#define GSTR 392   // gate_lds row stride (floats)

typedef __bf16 bf16x8 __attribute__((ext_vector_type(8)));
typedef float  f32x4  __attribute__((ext_vector_type(4)));

__device__ __forceinline__ unsigned short f2bf(float x) {
    union { float f; unsigned u; } v; v.f = x;
    unsigned r = v.u + 0x7fff + ((v.u >> 16) & 1);   // RNE
    return (unsigned short)(r >> 16);
}
__device__ __forceinline__ float bf2f(unsigned short h) {
    union { unsigned u; float f; } v; v.u = ((unsigned)h) << 16;
    return v.f;
}

// ---------------- pt table: pt[p][t] = path id, or -1 for padding ----------
__global__ void k_pt_init(int* __restrict__ pt) {
    int i = blockIdx.x * 256 + threadIdx.x;
    if (i < P_ * L_) pt[i] = -1;
}

__global__ void k_pt_scatter(const int* __restrict__ paths, const int* __restrict__ idx,
                             const int* __restrict__ seqs, int J, int* __restrict__ pt) {
    int j = blockIdx.x * 256 + threadIdx.x;
    if (j < J) pt[idx[j] * L_ + seqs[j]] = paths[j];
}

// ---------------- M = wq @ wk^T -------------------------------------------
__global__ __launch_bounds__(128) void k_M(const float* __restrict__ wq,
                                           const float* __restrict__ wk,
                                           float* __restrict__ M) {
    __shared__ float wk_lds[128 * 129];
    __shared__ float wq_row[128];
    int d = threadIdx.x;
    int j = blockIdx.x;
    wq_row[d] = wq[j * 128 + d];
    for (int r = 0; r < 128; ++r) wk_lds[r * 129 + d] = wk[r * 128 + d];
    __syncthreads();
    float acc = 0.f;
    for (int k = 0; k < 128; ++k) acc += wq_row[k] * wk_lds[d * 129 + k];
    M[j * 128 + d] = acc;
}

// ---------------- G[b*E+e][c] = bf16( inputs[b,e,:] @ W_in[:,c] + b_in[c] )
__global__ __launch_bounds__(384) void k_G(const float* __restrict__ inputs,
                                           const float* __restrict__ W_in,
                                           const float* __restrict__ b_in,
                                           unsigned short* __restrict__ G) {
    __shared__ __align__(16) float in_lds[16][128];
    int c = threadIdx.x;
    int row0 = blockIdx.x * 16;
    for (int i = c; i < 16 * 128; i += 384)
        in_lds[i >> 7][i & 127] = inputs[row0 * 128 + i];
    __syncthreads();
    float acc[16];
#pragma unroll
    for (int r = 0; r < 16; ++r) acc[r] = 0.f;
    for (int k = 0; k < 128; k += 4) {
        float w0 = W_in[(k + 0) * TD_ + c];
        float w1 = W_in[(k + 1) * TD_ + c];
        float w2 = W_in[(k + 2) * TD_ + c];
        float w3 = W_in[(k + 3) * TD_ + c];
#pragma unroll
        for (int r = 0; r < 16; ++r) {
            float4 h4 = *(const float4*)&in_lds[r][k];
            acc[r] += h4.x * w0 + h4.y * w1 + h4.z * w2 + h4.w * w3;
        }
    }
    float b = b_in[c];
#pragma unroll
    for (int r = 0; r < 16; ++r) G[(size_t)(row0 + r) * TD_ + c] = f2bf(acc[r] + b);
}

// ---------------- GRU recurrence, MFMA version -----------------------------
// block = 256 threads = 4 waves, 16 sequences per block.
// wave w computes gate cols [96w, 96w+96) via 6x4 MFMAs.
// B-fragments built in the preamble straight from W_rec (global input).
// h master copy in fp32 LDS; bf16 shadow for A-fragments.
__global__ __launch_bounds__(256, 2) void k_rec(const float* __restrict__ W_rec,
                                                const float* __restrict__ b_rec,
                                                const float* __restrict__ b_in,
                                                const unsigned short* __restrict__ G,
                                                const int* __restrict__ pt,
                                                unsigned short* __restrict__ hs) {
    __shared__ float gate_lds[16][GSTR];                       // 25088 B
    __shared__ float hf[16][128];                              // 8192 B
    __shared__ __align__(16) unsigned short hb[16][136];       // 4352 B
    __shared__ int pt_lds[16][16];                             // 1024 B

    int tid = threadIdx.x;
    int wv = tid >> 6, lane = tid & 63;
    int l15 = lane & 15, q = lane >> 4;
    int n0 = blockIdx.x * 16;
    int b  = n0 >> 11;           // n0 / P_
    int p0 = n0 & (P_ - 1);

    // ---- B-fragments from W_rec: bfrag[ct][kt][j] = W_rec[kt*32+q*8+j][ (6wv+ct)*16 + l15 ]
    bf16x8 bfrag[6][4];
#pragma unroll
    for (int ct = 0; ct < 6; ++ct) {
        int c = (6 * wv + ct) * 16 + l15;
#pragma unroll
        for (int kt = 0; kt < 4; ++kt) {
            int k0 = kt * 32 + q * 8;
            bf16x8 f;
#pragma unroll
            for (int j = 0; j < 8; ++j) {
                union { unsigned short s; __bf16 b; } cv;
                cv.s = f2bf(W_rec[(size_t)(k0 + j) * TD_ + c]);
                f[j] = cv.b;
            }
            bfrag[ct][kt] = f;
        }
    }

    pt_lds[tid >> 4][tid & 15] = pt[p0 * L_ + tid];
    for (int i = tid; i < 16 * 128; i += 256) {
        hf[i >> 7][i & 127] = 0.f;
        hb[i >> 7][i & 127] = 0;
    }

    int d  = tid & 127;
    int rg = tid >> 7;
    float bz = b_in[d], br = b_in[128 + d], bh = b_in[256 + d];
    float rz = b_rec[d], rr = b_rec[128 + d], rh = b_rec[256 + d];
    __syncthreads();

    for (int t = 0; t < L_; ++t) {
        // ---- A fragments from bf16 h shadow ----
        bf16x8 af[4];
#pragma unroll
        for (int kt = 0; kt < 4; ++kt)
            af[kt] = *(const bf16x8*)&hb[l15][kt * 32 + q * 8];

        // ---- MFMA: this wave's 96 gate cols ----
        f32x4 acc[6];
#pragma unroll
        for (int ct = 0; ct < 6; ++ct) {
            acc[ct] = (f32x4){0.f, 0.f, 0.f, 0.f};
#pragma unroll
            for (int kt = 0; kt < 4; ++kt)
                acc[ct] = __builtin_amdgcn_mfma_f32_16x16x32_bf16(af[kt], bfrag[ct][kt], acc[ct], 0, 0, 0);
        }

        // ---- C-layout -> gate_lds[row][col] ----
#pragma unroll
        for (int ct = 0; ct < 6; ++ct) {
            int c = 96 * wv + ct * 16 + l15;
#pragma unroll
            for (int j = 0; j < 4; ++j)
                gate_lds[q * 4 + j][c] = acc[ct][j];
        }
        __syncthreads();

        // ---- epilogue: thread owns (d, rows rg*8..rg*8+7) ----
        float xz[8], xr[8], xh[8];
#pragma unroll
        for (int i = 0; i < 8; ++i) {
            int e = pt_lds[rg * 8 + i][t];
            if (e >= 0) {
                const unsigned short* g = G + (size_t)(b * E_ + e) * TD_;
                xz[i] = bf2f(g[d]); xr[i] = bf2f(g[128 + d]); xh[i] = bf2f(g[256 + d]);
            } else {
                xz[i] = bz; xr[i] = br; xh[i] = bh;
            }
        }
#pragma unroll
        for (int i = 0; i < 8; ++i) {
            int r = rg * 8 + i;
            float az = gate_lds[r][d] + rz;
            float ar = gate_lds[r][128 + d] + rr;
            float ah = gate_lds[r][256 + d] + rh;
            float z  = 1.f / (1.f + __expf(-(xz[i] + az)));
            float rgt = 1.f / (1.f + __expf(-(xr[i] + ar)));
            float pre = xh[i] + rgt * ah;
            float t2 = __expf(-2.f * fabsf(pre));
            float th = (1.f - t2) / (1.f + t2);
            float hc = (pre >= 0.f) ? th : -th;
            float hp = hf[r][d];
            float hn = z * hp + (1.f - z) * hc;
            hf[r][d] = hn;
            unsigned short hbits = f2bf(hn);
            hb[r][d] = hbits;
            hs[((size_t)(n0 + r) * L_ + t) * D_ + d] = hbits;
        }
        __syncthreads();
    }
}

// ---------------- attention ------------------------------------------------
__global__ __launch_bounds__(128) void k_att(const __hip_bfloat16* __restrict__ hs,
                                             const float* __restrict__ M,
                                             const float* __restrict__ wv,
                                             float* __restrict__ out) {
    __shared__ float last_lds[4][128];
    __shared__ float s_lds[4][128];
    __shared__ float red[8];
    int d = threadIdx.x;
    int n0 = blockIdx.x * 4;
    int wave = d >> 6, lane = d & 63;

#pragma unroll
    for (int r = 0; r < 4; ++r)
        last_lds[r][d] = __bfloat162float(hs[((size_t)(n0 + r) * L_ + 15) * D_ + d]);
    __syncthreads();

    float qk[4] = {0.f, 0.f, 0.f, 0.f};
    for (int k = 0; k < 128; ++k) {
        float mv = M[k * 128 + d];
#pragma unroll
        for (int r = 0; r < 4; ++r) qk[r] += last_lds[r][k] * mv;
    }

    float s[4] = {0.f, 0.f, 0.f, 0.f};
    for (int l = 0; l < L_; ++l) {
        float hv[4], p[4];
#pragma unroll
        for (int r = 0; r < 4; ++r) {
            hv[r] = __bfloat162float(hs[((size_t)(n0 + r) * L_ + l) * D_ + d]);
            p[r] = hv[r] * qk[r];
        }
#pragma unroll
        for (int r = 0; r < 4; ++r) {
            float v = p[r];
            for (int o = 32; o > 0; o >>= 1) v += __shfl_down(v, o, 64);
            if (lane == 0) red[wave * 4 + r] = v;
        }
        __syncthreads();
#pragma unroll
        for (int r = 0; r < 4; ++r) {
            float att = red[r] + red[4 + r];
            s[r] += att * hv[r];
        }
        __syncthreads();
    }

#pragma unroll
    for (int r = 0; r < 4; ++r) s_lds[r][d] = s[r];
    __syncthreads();
    float c4[4] = {0.f, 0.f, 0.f, 0.f};
    for (int k = 0; k < 128; ++k) {
        float wvv = wv[k * 128 + d];
#pragma unroll
        for (int r = 0; r < 4; ++r) c4[r] += s_lds[r][k] * wvv;
    }
#pragma unroll
    for (int r = 0; r < 4; ++r) out[(size_t)(n0 + r) * D_ + d] = c4[r];
}

// ---------------------------------------------------------------------------
extern "C" void kernel_launch(void* const* d_in, const int* in_sizes, int n_in,
                              void* d_out, int out_size, void* d_ws, size_t ws_size,
                              hipStream_t stream) {
    const float* inputs = (const float*)d_in[0];
    const float* W_in   = (const float*)d_in[1];
    const float* W_rec  = (const float*)d_in[2];
    const float* b_in   = (const float*)d_in[3];
    const float* b_rec  = (const float*)d_in[4];
    const float* wq     = (const float*)d_in[5];
    const float* wk     = (const float*)d_in[6];
    const float* wvp    = (const float*)d_in[7];
    const int* paths    = (const int*)d_in[8];
    const int* idx      = (const int*)d_in[9];
    const int* seqs     = (const int*)d_in[10];
    int J = in_sizes[8];

    // workspace layout: 131072 + 65536 + 12582912 + 134217728 = 146,997,248 B (~140.2 MiB)
    const size_t off_pt = 0;
    const size_t off_M  = off_pt + (size_t)P_ * L_ * sizeof(int);
    const size_t off_G  = off_M + 128 * 128 * sizeof(float);
    const size_t off_hs = off_G + (size_t)B_ * E_ * TD_ * sizeof(short);
    char* ws = (char*)d_ws;
    int*   pt = (int*)(ws + off_pt);
    float* M  = (float*)(ws + off_M);
    unsigned short* G  = (unsigned short*)(ws + off_G);
    unsigned short* hs = (unsigned short*)(ws + off_hs);
    float* out = (float*)d_out;

    k_pt_init<<<dim3((P_ * L_ + 255) / 256), dim3(256), 0, stream>>>(pt);
    k_pt_scatter<<<dim3((J + 255) / 256), dim3(256), 0, stream>>>(paths, idx, seqs, J, pt);
    k_M<<<dim3(128), dim3(128), 0, stream>>>(wq, wk, M);
    k_G<<<dim3(B_ * E_ / 16), dim3(384), 0, stream>>>(inputs, W_in, b_in, G);
    k_rec<<<dim3(B_ * P_ / 16), dim3(256), 0, stream>>>(W_rec, b_rec, b_in, G, pt, hs);
    k_att<<<dim3(B_ * P_ / 4), dim3(128), 0, stream>>>((const __hip_bfloat16*)hs, M, wvp, out);
}

// Round 4
// 307.123 us; speedup vs baseline: 4.1900x; 1.6428x over previous
//
#include <hip/hip_runtime.h>
#include <hip/hip_bf16.h>
#include <cstddef>

#define P_   2048
#define B_   16
#define E_   1024
#define D_   128
#define L_   16
#define TD_  384   // 3*D
#define GBSTR 106  // per-wave gate buffer row stride (floats): stores 2-way, reads 2-way (free)

typedef __bf16 bf16x8 __attribute__((ext_vector_type(8)));
typedef float  f32x4  __attribute__((ext_vector_type(4)));
typedef unsigned short ushort8 __attribute__((ext_vector_type(8)));

__device__ __forceinline__ unsigned short f2bf(float x) {
    union { float f; unsigned u; } v; v.f = x;
    unsigned r = v.u + 0x7fff + ((v.u >> 16) & 1);   // RNE
    return (unsigned short)(r >> 16);
}
__device__ __forceinline__ float bf2f(unsigned x) {
    union { unsigned u; float f; } v; v.u = x << 16;
    return v.f;
}

// ---------------- pt table ------------------------------------------------
__global__ void k_pt_init(int* __restrict__ pt) {
    int i = blockIdx.x * 256 + threadIdx.x;
    if (i < P_ * L_) pt[i] = -1;
}
__global__ void k_pt_scatter(const int* __restrict__ paths, const int* __restrict__ idx,
                             const int* __restrict__ seqs, int J, int* __restrict__ pt) {
    int j = blockIdx.x * 256 + threadIdx.x;
    if (j < J) pt[idx[j] * L_ + seqs[j]] = paths[j];
}

// ---------------- M = wq @ wk^T (fp32) ------------------------------------
__global__ __launch_bounds__(128) void k_M(const float* __restrict__ wq,
                                           const float* __restrict__ wk,
                                           float* __restrict__ M) {
    __shared__ float wk_lds[128 * 129];
    __shared__ float wq_row[128];
    int d = threadIdx.x;
    int j = blockIdx.x;
    wq_row[d] = wq[j * 128 + d];
    for (int r = 0; r < 128; ++r) wk_lds[r * 129 + d] = wk[r * 128 + d];
    __syncthreads();
    float acc = 0.f;
    for (int k = 0; k < 128; ++k) acc += wq_row[k] * wk_lds[d * 129 + k];
    M[j * 128 + d] = acc;
}

// ---------------- generic fp32 [128][N] -> bf16 MFMA B-fragment swizzle ----
// frag[(tile*4+kt)*64 + lane][j] = bf16( src[(kt*32 + (lane>>4)*8 + j)][tile*16 + (lane&15)] )
__global__ void k_wf(const float* __restrict__ src, unsigned short* __restrict__ dst, int NT) {
    int g = blockIdx.x * 256 + threadIdx.x;
    if (g >= NT * 256) return;
    int lane = g & 63, kt = (g >> 6) & 3, tile = g >> 8;
    int N = NT * 16;
    int k0 = kt * 32 + (lane >> 4) * 8;
    int c = tile * 16 + (lane & 15);
#pragma unroll
    for (int j = 0; j < 8; ++j)
        dst[(size_t)g * 8 + j] = f2bf(src[(size_t)(k0 + j) * N + c]);
}

// ---------------- k_G: G2[row][d][4] = {z,r,h,pad} via MFMA ----------------
__global__ __launch_bounds__(256) void k_G(const float* __restrict__ inputs,
                                           const unsigned short* __restrict__ WfI,
                                           const float* __restrict__ b_in,
                                           unsigned short* __restrict__ G2) {
    __shared__ __align__(16) unsigned short a_lds[16][136];
    int tid = threadIdx.x, w = tid >> 6, L = tid & 63;
    int l15 = L & 15, q = L >> 4;
    int row0 = blockIdx.x * 16;

    // stage 16x128 fp32 -> bf16 LDS; thread tid handles 8 elems (row tid>>4, col (tid&15)*8)
    {
        int r = tid >> 4, c = (tid & 15) * 8;
        const float4* p = (const float4*)(inputs + (size_t)(row0 + r) * 128 + c);
        float4 v0 = p[0], v1 = p[1];
        ushort8 t8;
        t8[0] = f2bf(v0.x); t8[1] = f2bf(v0.y); t8[2] = f2bf(v0.z); t8[3] = f2bf(v0.w);
        t8[4] = f2bf(v1.x); t8[5] = f2bf(v1.y); t8[6] = f2bf(v1.z); t8[7] = f2bf(v1.w);
        *(ushort8*)&a_lds[r][c] = t8;
    }
    __syncthreads();

    bf16x8 af[4];
#pragma unroll
    for (int kt = 0; kt < 4; ++kt)
        af[kt] = *(const bf16x8*)&a_lds[l15][kt * 32 + q * 8];

#pragma unroll
    for (int ct = 0; ct < 6; ++ct) {
        int tl = 6 * w + ct;
        f32x4 acc = (f32x4){0.f, 0.f, 0.f, 0.f};
#pragma unroll
        for (int kt = 0; kt < 4; ++kt)
            acc = __builtin_amdgcn_mfma_f32_16x16x32_bf16(
                af[kt], *(const bf16x8*)(WfI + (size_t)((tl * 4 + kt) * 64 + L) * 8), acc, 0, 0, 0);
        int g  = tl >> 3;                   // gate index 0..2
        int dd = (tl & 7) * 16 + l15;       // d 0..127
        float bia = b_in[tl * 16 + l15];
#pragma unroll
        for (int j = 0; j < 4; ++j) {
            int r = q * 4 + j;
            G2[((size_t)(row0 + r) * 128 + dd) * 4 + g] = f2bf(acc[j] + bia);
        }
    }
}

// ---------------- GRU recurrence: wave-local gates + G prefetch ------------
// block 256 = 4 waves, 16 seqs. Wave w owns gate cols d in [32w,32w+32) for z/r/h.
__global__ __launch_bounds__(256) void k_rec(const unsigned short* __restrict__ WfR,
                                             const float* __restrict__ b_rec,
                                             const float* __restrict__ b_in,
                                             const unsigned short* __restrict__ G2,
                                             const int* __restrict__ pt,
                                             unsigned short* __restrict__ hs) {
    __shared__ float gbuf[4][16][GBSTR];                 // 27136 B, per-wave regions
    __shared__ __align__(16) unsigned short hb[16][136]; // 4352 B, bf16 h shadow
    __shared__ int pt_lds[16][16];                       // 1024 B

    int tid = threadIdx.x, w = tid >> 6, L = tid & 63;
    int l15 = L & 15, q = L >> 4, d31 = L & 31;
    int d = 32 * w + d31;
    int rb = (L >> 5) * 8;                  // epilogue row group base
    int n0 = blockIdx.x * 16;
    int b  = n0 >> 11;
    int p0 = n0 & (P_ - 1);

    // B-fragments for this wave's 6 tiles (z,z,r,r,h,h)
    const int tiles[6] = {2 * w, 2 * w + 1, 8 + 2 * w, 9 + 2 * w, 16 + 2 * w, 17 + 2 * w};
    bf16x8 bfrag[6][4];
#pragma unroll
    for (int ct = 0; ct < 6; ++ct)
#pragma unroll
        for (int kt = 0; kt < 4; ++kt)
            bfrag[ct][kt] = *(const bf16x8*)(WfR + (size_t)((tiles[ct] * 4 + kt) * 64 + L) * 8);

    pt_lds[tid >> 4][tid & 15] = pt[p0 * L_ + tid];
    for (int i = tid; i < 16 * 128; i += 256) hb[i >> 7][i & 127] = 0;

    float bz = b_in[d], br = b_in[128 + d], bh = b_in[256 + d];
    float rz = b_rec[d], rr = b_rec[128 + d], rh = b_rec[256 + d];
    float h_reg[8];
#pragma unroll
    for (int i = 0; i < 8; ++i) h_reg[i] = 0.f;
    __syncthreads();

    const unsigned short* g2base = G2 + (size_t)b * E_ * 512 + (size_t)d * 4;

    uint2 cur[8];
#pragma unroll
    for (int i = 0; i < 8; ++i) {
        int e = pt_lds[rb + i][0];
        uint2 v = make_uint2(0u, 0u);
        if (e >= 0) v = *(const uint2*)(g2base + (size_t)e * 512);
        cur[i] = v;
    }

    for (int t = 0; t < L_; ++t) {
        // prefetch next step's G rows (addresses known from pt)
        uint2 nxt[8];
#pragma unroll
        for (int i = 0; i < 8; ++i) nxt[i] = make_uint2(0u, 0u);
        if (t < 15) {
#pragma unroll
            for (int i = 0; i < 8; ++i) {
                int e = pt_lds[rb + i][t + 1];
                if (e >= 0) nxt[i] = *(const uint2*)(g2base + (size_t)e * 512);
            }
        }

        // A fragments from bf16 h shadow
        bf16x8 af[4];
#pragma unroll
        for (int kt = 0; kt < 4; ++kt)
            af[kt] = *(const bf16x8*)&hb[l15][kt * 32 + q * 8];

        // MFMA: this wave's 96 gate cols (z/r/h for d in [32w,32w+32))
        f32x4 acc[6];
#pragma unroll
        for (int ct = 0; ct < 6; ++ct) {
            acc[ct] = (f32x4){0.f, 0.f, 0.f, 0.f};
#pragma unroll
            for (int kt = 0; kt < 4; ++kt)
                acc[ct] = __builtin_amdgcn_mfma_f32_16x16x32_bf16(af[kt], bfrag[ct][kt], acc[ct], 0, 0, 0);
        }

        // C -> wave-local gate buffer (local cols: z 0..31, r 32..63, h 64..95)
#pragma unroll
        for (int ct = 0; ct < 6; ++ct) {
            int lc = ct * 16 + l15;
#pragma unroll
            for (int j = 0; j < 4; ++j)
                gbuf[w][q * 4 + j][lc] = acc[ct][j];
        }
        // wave-local visibility: same-wave DS ops are in-order; block compiler reordering
        __builtin_amdgcn_wave_barrier();
        __builtin_amdgcn_s_waitcnt(0xC07F);   // lgkmcnt(0) only; leaves vmcnt (prefetch) in flight
        __builtin_amdgcn_wave_barrier();

        // epilogue: thread owns (col d, rows rb..rb+7)
#pragma unroll
        for (int i = 0; i < 8; ++i) {
            int r = rb + i;
            int e = pt_lds[r][t];
            float xz, xr, xh;
            if (e >= 0) {
                unsigned a = cur[i].x, bb = cur[i].y;
                xz = bf2f(a & 0xffffu); xr = bf2f(a >> 16); xh = bf2f(bb & 0xffffu);
            } else {
                xz = bz; xr = br; xh = bh;
            }
            float az = gbuf[w][r][d31] + rz;
            float ar = gbuf[w][r][32 + d31] + rr;
            float ah = gbuf[w][r][64 + d31] + rh;
            float z   = __builtin_amdgcn_rcpf(1.f + __expf(-(xz + az)));
            float rgt = __builtin_amdgcn_rcpf(1.f + __expf(-(xr + ar)));
            float pre = xh + rgt * ah;
            float hc  = 1.f - 2.f * __builtin_amdgcn_rcpf(__expf(2.f * pre) + 1.f);
            float hn  = z * h_reg[i] + (1.f - z) * hc;
            h_reg[i] = hn;
            unsigned short hbits = f2bf(hn);
            hb[r][d] = hbits;
            hs[((size_t)(n0 + r) * L_ + t) * D_ + d] = hbits;
            cur[i] = nxt[i];
        }
        __syncthreads();   // hb complete before next step's A reads
    }
}

// ---------------- k_att: 8 seqs/block, MFMA for qk and ctx@wv --------------
__global__ __launch_bounds__(128) void k_att(const unsigned short* __restrict__ hs,
                                             const unsigned short* __restrict__ Mf,
                                             const unsigned short* __restrict__ wvf,
                                             float* __restrict__ out) {
    __shared__ __align__(16) unsigned short hsl[128][136];  // 8 seqs x 16 steps
    __shared__ float qk[8][132];
    __shared__ float attl[8][20];
    __shared__ __align__(16) unsigned short svb[8][136];

    int tid = threadIdx.x, w = tid >> 6, L = tid & 63;
    int l15 = L & 15, q = L >> 4;
    int n0 = blockIdx.x * 8;

    // stage: thread tid stages row tid (seq tid>>4, step tid&15)
    {
        const unsigned short* src = hs + ((size_t)(n0 + (tid >> 4)) * L_ + (tid & 15)) * D_;
#pragma unroll
        for (int c = 0; c < 128; c += 8)
            *(ushort8*)&hsl[tid][c] = *(const ushort8*)(src + c);
    }
    __syncthreads();

    // qk[s][:] = last[s] @ M  (MFMA; A rows duplicated l15&7, C rows>=8 dropped)
    {
        bf16x8 af[4];
#pragma unroll
        for (int kt = 0; kt < 4; ++kt)
            af[kt] = *(const bf16x8*)&hsl[(l15 & 7) * 16 + 15][kt * 32 + q * 8];
#pragma unroll
        for (int i = 0; i < 4; ++i) {
            int tl = 4 * w + i;
            f32x4 acc = (f32x4){0.f, 0.f, 0.f, 0.f};
#pragma unroll
            for (int kt = 0; kt < 4; ++kt)
                acc = __builtin_amdgcn_mfma_f32_16x16x32_bf16(
                    af[kt], *(const bf16x8*)(Mf + (size_t)((tl * 4 + kt) * 64 + L) * 8), acc, 0, 0, 0);
#pragma unroll
            for (int j = 0; j < 4; ++j) {
                int s = q * 4 + j;
                if (s < 8) qk[s][tl * 16 + l15] = acc[j];
            }
        }
    }
    __syncthreads();

    // att[s][l] = hs[s][l][:] . qk[s][:]
    {
        int s = tid >> 4, l = tid & 15;
        const unsigned short* hr = &hsl[s * 16 + l][0];
        float a = 0.f;
        for (int k = 0; k < 128; k += 2) {
            unsigned pp = *(const unsigned*)(hr + k);
            float2 qq = *(const float2*)&qk[s][k];
            a += bf2f(pp & 0xffffu) * qq.x + bf2f(pp >> 16) * qq.y;
        }
        attl[s][l] = a;
    }
    __syncthreads();

    // svec[s][d] = sum_l att[s][l] * hs[s][l][d]  -> bf16
    {
        int s = tid >> 4, o = tid & 15, d0 = o * 8;
        float v[8];
#pragma unroll
        for (int j = 0; j < 8; ++j) v[j] = 0.f;
        for (int l = 0; l < 16; ++l) {
            float a = attl[s][l];
            ushort8 hh = *(const ushort8*)&hsl[s * 16 + l][d0];
#pragma unroll
            for (int j = 0; j < 8; ++j) v[j] += a * bf2f((unsigned)(unsigned short)hh[j]);
        }
        ushort8 t8;
#pragma unroll
        for (int j = 0; j < 8; ++j) t8[j] = f2bf(v[j]);
        *(ushort8*)&svb[s][d0] = t8;
    }
    __syncthreads();

    // ctx = svec @ wv  (MFMA)
    {
        bf16x8 af[4];
#pragma unroll
        for (int kt = 0; kt < 4; ++kt)
            af[kt] = *(const bf16x8*)&svb[l15 & 7][kt * 32 + q * 8];
#pragma unroll
        for (int i = 0; i < 4; ++i) {
            int tl = 4 * w + i;
            f32x4 acc = (f32x4){0.f, 0.f, 0.f, 0.f};
#pragma unroll
            for (int kt = 0; kt < 4; ++kt)
                acc = __builtin_amdgcn_mfma_f32_16x16x32_bf16(
                    af[kt], *(const bf16x8*)(wvf + (size_t)((tl * 4 + kt) * 64 + L) * 8), acc, 0, 0, 0);
#pragma unroll
            for (int j = 0; j < 4; ++j) {
                int s = q * 4 + j;
                if (s < 8) out[(size_t)(n0 + s) * D_ + tl * 16 + l15] = acc[j];
            }
        }
    }
}

// ---------------------------------------------------------------------------
extern "C" void kernel_launch(void* const* d_in, const int* in_sizes, int n_in,
                              void* d_out, int out_size, void* d_ws, size_t ws_size,
                              hipStream_t stream) {
    const float* inputs = (const float*)d_in[0];
    const float* W_in   = (const float*)d_in[1];
    const float* W_rec  = (const float*)d_in[2];
    const float* b_in   = (const float*)d_in[3];
    const float* b_rec  = (const float*)d_in[4];
    const float* wq     = (const float*)d_in[5];
    const float* wk     = (const float*)d_in[6];
    const float* wvp    = (const float*)d_in[7];
    const int* paths    = (const int*)d_in[8];
    const int* idx      = (const int*)d_in[9];
    const int* seqs     = (const int*)d_in[10];
    int J = in_sizes[8];

    // ws layout (bytes), total = 151,463,696 (~144.4 MiB)
    const size_t off_pt  = 0;
    const size_t off_M   = off_pt  + (size_t)P_ * L_ * 4;      // 131072
    const size_t off_WfR = off_M   + 128 * 128 * 4;            // +65536
    const size_t off_WfI = off_WfR + (size_t)24 * 256 * 8 * 2; // +98304
    const size_t off_Mf  = off_WfI + (size_t)24 * 256 * 8 * 2; // +98304
    const size_t off_wvf = off_Mf  + (size_t)8 * 256 * 8 * 2;  // +32768
    const size_t off_G2  = off_wvf + (size_t)8 * 256 * 8 * 2;  // +32768
    const size_t off_hs  = off_G2  + (size_t)B_ * E_ * 128 * 4 * 2; // +16777216
    char* ws = (char*)d_ws;
    int*   pt = (int*)(ws + off_pt);
    float* M  = (float*)(ws + off_M);
    unsigned short* WfR = (unsigned short*)(ws + off_WfR);
    unsigned short* WfI = (unsigned short*)(ws + off_WfI);
    unsigned short* Mf  = (unsigned short*)(ws + off_Mf);
    unsigned short* wvf = (unsigned short*)(ws + off_wvf);
    unsigned short* G2  = (unsigned short*)(ws + off_G2);
    unsigned short* hs  = (unsigned short*)(ws + off_hs);
    float* out = (float*)d_out;

    k_pt_init<<<dim3(P_ * L_ / 256), dim3(256), 0, stream>>>(pt);
    k_pt_scatter<<<dim3((J + 255) / 256), dim3(256), 0, stream>>>(paths, idx, seqs, J, pt);
    k_M<<<dim3(128), dim3(128), 0, stream>>>(wq, wk, M);
    k_wf<<<dim3(24), dim3(256), 0, stream>>>(W_rec, WfR, 24);
    k_wf<<<dim3(24), dim3(256), 0, stream>>>(W_in,  WfI, 24);
    k_wf<<<dim3(8),  dim3(256), 0, stream>>>(M,     Mf,   8);
    k_wf<<<dim3(8),  dim3(256), 0, stream>>>(wvp,   wvf,  8);
    k_G<<<dim3(B_ * E_ / 16), dim3(256), 0, stream>>>(inputs, WfI, b_in, G2);
    k_rec<<<dim3(B_ * P_ / 16), dim3(256), 0, stream>>>(WfR, b_rec, b_in, G2, pt, hs);
    k_att<<<dim3(B_ * P_ / 8), dim3(128), 0, stream>>>(hs, Mf, wvf, out);
}

// Round 5
// 269.393 us; speedup vs baseline: 4.7768x; 1.1401x over previous
//
#include <hip/hip_runtime.h>
#include <hip/hip_bf16.h>
#include <cstddef>

#define P_ 2048
#define B_ 16
#define E_ 1024
#define D_ 128
#define L_ 16
#define TD_ 384

typedef __bf16 bf16x8 __attribute__((ext_vector_type(8)));
typedef float  f32x4  __attribute__((ext_vector_type(4)));
typedef unsigned short ushort8 __attribute__((ext_vector_type(8)));

__device__ __forceinline__ unsigned short f2bf(float x) {
    union { float f; unsigned u; } v; v.f = x;
    unsigned r = v.u + 0x7fff + ((v.u >> 16) & 1);   // RNE
    return (unsigned short)(r >> 16);
}
__device__ __forceinline__ float bf2f(unsigned x) {
    union { unsigned u; float f; } v; v.u = x << 16;
    return v.f;
}

// ---- B-fragment swizzles: frag[(tile*4+kt)*64+lane][j] = src[k0+j][tile*16+(lane&15)]
__device__ __forceinline__ void wf_body(const float* __restrict__ src,
                                        unsigned short* __restrict__ dst, int g, int N) {
    int lane = g & 63, kt = (g >> 6) & 3, tile = g >> 8;
    int k0 = kt * 32 + (lane >> 4) * 8;
    int c = tile * 16 + (lane & 15);
#pragma unroll
    for (int j = 0; j < 8; ++j)
        dst[(size_t)g * 8 + j] = f2bf(src[(size_t)(k0 + j) * N + c]);
}
// transposed source (for wk^T): B[k][n] = src[n][k], src 128x128
__device__ __forceinline__ void wfT_body(const float* __restrict__ src,
                                         unsigned short* __restrict__ dst, int g) {
    int lane = g & 63, kt = (g >> 6) & 3, tile = g >> 8;
    int k0 = kt * 32 + (lane >> 4) * 8;
    int c = tile * 16 + (lane & 15);
#pragma unroll
    for (int j = 0; j < 8; ++j)
        dst[(size_t)g * 8 + j] = f2bf(src[(size_t)c * 128 + k0 + j]);
}

// ---- k_prep: pt init + all weight swizzles, one launch (200 blocks) -------
__global__ __launch_bounds__(256) void k_prep(const float* __restrict__ W_rec,
                                              const float* __restrict__ W_in,
                                              const float* __restrict__ wq,
                                              const float* __restrict__ wk,
                                              const float* __restrict__ wv,
                                              int* __restrict__ pt,
                                              unsigned short* __restrict__ WfR,
                                              unsigned short* __restrict__ WfI,
                                              unsigned short* __restrict__ wqf,
                                              unsigned short* __restrict__ wkTf,
                                              unsigned short* __restrict__ wvf) {
    int blk = blockIdx.x, tid = threadIdx.x;
    if      (blk < 128) pt[blk * 256 + tid] = -1;                       // 32768 entries
    else if (blk < 152) wf_body(W_rec, WfR, (blk - 128) * 256 + tid, TD_);
    else if (blk < 176) wf_body(W_in,  WfI, (blk - 152) * 256 + tid, TD_);
    else if (blk < 184) wf_body(wq,    wqf, (blk - 176) * 256 + tid, 128);
    else if (blk < 192) wfT_body(wk,  wkTf, (blk - 184) * 256 + tid);
    else                wf_body(wv,    wvf, (blk - 192) * 256 + tid, 128);
}

// ---- k_G: G2[row][d][4]={z,r,h,pad} via MFMA; tail blocks do pt scatter ---
__global__ __launch_bounds__(256) void k_G(const float* __restrict__ inputs,
                                           const unsigned short* __restrict__ WfI,
                                           const float* __restrict__ b_in,
                                           unsigned short* __restrict__ G2,
                                           const int* __restrict__ paths,
                                           const int* __restrict__ idx,
                                           const int* __restrict__ seqs, int J,
                                           int* __restrict__ pt) {
    if (blockIdx.x >= 1024) {   // pt scatter tail
        int j = (blockIdx.x - 1024) * 256 + threadIdx.x;
        if (j < J) pt[idx[j] * L_ + seqs[j]] = paths[j];
        return;
    }
    __shared__ __align__(16) unsigned short a_lds[16][136];
    int tid = threadIdx.x, w = tid >> 6, L = tid & 63;
    int l15 = L & 15, q = L >> 4;
    int row0 = blockIdx.x * 16;
    {
        int r = tid >> 4, c = (tid & 15) * 8;
        const float4* p = (const float4*)(inputs + (size_t)(row0 + r) * 128 + c);
        float4 v0 = p[0], v1 = p[1];
        ushort8 t8;
        t8[0] = f2bf(v0.x); t8[1] = f2bf(v0.y); t8[2] = f2bf(v0.z); t8[3] = f2bf(v0.w);
        t8[4] = f2bf(v1.x); t8[5] = f2bf(v1.y); t8[6] = f2bf(v1.z); t8[7] = f2bf(v1.w);
        *(ushort8*)&a_lds[r][c] = t8;
    }
    __syncthreads();
    bf16x8 af[4];
#pragma unroll
    for (int kt = 0; kt < 4; ++kt)
        af[kt] = *(const bf16x8*)&a_lds[l15][kt * 32 + q * 8];
#pragma unroll
    for (int ct = 0; ct < 6; ++ct) {
        int tl = 6 * w + ct;
        f32x4 acc = (f32x4){0.f, 0.f, 0.f, 0.f};
#pragma unroll
        for (int kt = 0; kt < 4; ++kt)
            acc = __builtin_amdgcn_mfma_f32_16x16x32_bf16(
                af[kt], *(const bf16x8*)(WfI + (size_t)((tl * 4 + kt) * 64 + L) * 8), acc, 0, 0, 0);
        int g  = tl >> 3;
        int dd = (tl & 7) * 16 + l15;
        float bia = b_in[tl * 16 + l15];
#pragma unroll
        for (int j = 0; j < 4; ++j) {
            int r = q * 4 + j;
            G2[((size_t)(row0 + r) * 128 + dd) * 4 + g] = f2bf(acc[j] + bia);
        }
    }
}

// ---- GRU recurrence: gates consumed directly from MFMA acc registers ------
// block 256 = 4 waves, 16 seqs. Wave w: gate cols d in [32w,32w+32).
// Lane (q,l15) owns rows q*4..q*4+3 x cols {32w+l15, 32w+l15+16} == its C-layout slots.
__global__ __launch_bounds__(256) void k_rec(const unsigned short* __restrict__ WfR,
                                             const float* __restrict__ b_rec,
                                             const float* __restrict__ b_in,
                                             const unsigned short* __restrict__ G2,
                                             const int* __restrict__ pt,
                                             unsigned short* __restrict__ hs) {
    __shared__ __align__(16) unsigned short hb[2][16][136];   // ping-pong bf16 h
    __shared__ int pt_lds[16][16];

    int tid = threadIdx.x, w = tid >> 6, L = tid & 63;
    int l15 = L & 15, q = L >> 4;
    int c0 = 32 * w + l15, c1 = c0 + 16;
    int n0 = blockIdx.x * 16;
    int b  = n0 >> 11;
    int p0 = n0 & (P_ - 1);

    const int tiles[6] = {2 * w, 2 * w + 1, 8 + 2 * w, 9 + 2 * w, 16 + 2 * w, 17 + 2 * w};
    bf16x8 bfrag[6][4];
#pragma unroll
    for (int ct = 0; ct < 6; ++ct)
#pragma unroll
        for (int kt = 0; kt < 4; ++kt)
            bfrag[ct][kt] = *(const bf16x8*)(WfR + (size_t)((tiles[ct] * 4 + kt) * 64 + L) * 8);

    pt_lds[tid >> 4][tid & 15] = pt[p0 * L_ + tid];
    for (int i = tid; i < 2048; i += 256) hb[0][i >> 7][i & 127] = 0;

    float bz0 = b_in[c0], br0 = b_in[128 + c0], bh0 = b_in[256 + c0];
    float bz1 = b_in[c1], br1 = b_in[128 + c1], bh1 = b_in[256 + c1];
    float rz0 = b_rec[c0], rr0 = b_rec[128 + c0], rh0 = b_rec[256 + c0];
    float rz1 = b_rec[c1], rr1 = b_rec[128 + c1], rh1 = b_rec[256 + c1];
    float h_reg[8];
#pragma unroll
    for (int i = 0; i < 8; ++i) h_reg[i] = 0.f;
    __syncthreads();

    const unsigned short* g2b = G2 + (size_t)b * E_ * 512;

    uint2 cur[4][2];
#pragma unroll
    for (int j = 0; j < 4; ++j) {
        int e = pt_lds[q * 4 + j][0];
        cur[j][0] = make_uint2(0u, 0u); cur[j][1] = make_uint2(0u, 0u);
        if (e >= 0) {
            const unsigned short* gp = g2b + (size_t)e * 512;
            cur[j][0] = *(const uint2*)(gp + c0 * 4);
            cur[j][1] = *(const uint2*)(gp + c1 * 4);
        }
    }

    for (int t = 0; t < L_; ++t) {
        // A fragments from current h buffer
        bf16x8 af[4];
#pragma unroll
        for (int kt = 0; kt < 4; ++kt)
            af[kt] = *(const bf16x8*)&hb[t & 1][l15][kt * 32 + q * 8];

        // prefetch next step's G rows
        uint2 nxt[4][2];
#pragma unroll
        for (int j = 0; j < 4; ++j) { nxt[j][0] = make_uint2(0u, 0u); nxt[j][1] = make_uint2(0u, 0u); }
        if (t < 15) {
#pragma unroll
            for (int j = 0; j < 4; ++j) {
                int e = pt_lds[q * 4 + j][t + 1];
                if (e >= 0) {
                    const unsigned short* gp = g2b + (size_t)e * 512;
                    nxt[j][0] = *(const uint2*)(gp + c0 * 4);
                    nxt[j][1] = *(const uint2*)(gp + c1 * 4);
                }
            }
        }

        // MFMA: z (acc0/1), r (acc2/3), h (acc4/5) for this wave's 32 cols
        f32x4 acc[6];
#pragma unroll
        for (int ct = 0; ct < 6; ++ct) {
            acc[ct] = (f32x4){0.f, 0.f, 0.f, 0.f};
#pragma unroll
            for (int kt = 0; kt < 4; ++kt)
                acc[ct] = __builtin_amdgcn_mfma_f32_16x16x32_bf16(af[kt], bfrag[ct][kt], acc[ct], 0, 0, 0);
        }

        // epilogue: straight from acc registers, no LDS gate buffer
#pragma unroll
        for (int j = 0; j < 4; ++j) {
            int row = q * 4 + j;
            int e = pt_lds[row][t];
#pragma unroll
            for (int half = 0; half < 2; ++half) {
                float xz, xr, xh;
                if (e >= 0) {
                    unsigned a = cur[j][half].x, bb = cur[j][half].y;
                    xz = bf2f(a & 0xffffu); xr = bf2f(a >> 16); xh = bf2f(bb & 0xffffu);
                } else {
                    xz = half ? bz1 : bz0; xr = half ? br1 : br0; xh = half ? bh1 : bh0;
                }
                float az = acc[half][j]     + (half ? rz1 : rz0);
                float ar = acc[2 + half][j] + (half ? rr1 : rr0);
                float ah = acc[4 + half][j] + (half ? rh1 : rh0);
                float z   = __builtin_amdgcn_rcpf(1.f + __expf(-(xz + az)));
                float rg  = __builtin_amdgcn_rcpf(1.f + __expf(-(xr + ar)));
                float pre = xh + rg * ah;
                float hc  = 1.f - 2.f * __builtin_amdgcn_rcpf(__expf(2.f * pre) + 1.f);
                float hn  = z * h_reg[j * 2 + half] + (1.f - z) * hc;
                h_reg[j * 2 + half] = hn;
                unsigned short hbits = f2bf(hn);
                int c = half ? c1 : c0;
                hb[(t + 1) & 1][row][c] = hbits;
                hs[((size_t)(n0 + row) * L_ + t) * D_ + c] = hbits;
                cur[j][half] = nxt[j][half];
            }
        }
        __syncthreads();   // hb[(t+1)&1] complete before next step's A reads
    }
}

// ---- k_att: qk = (last@wq)@wk^T, att/svec VALU, ctx = svec@wv -------------
__global__ __launch_bounds__(128) void k_att(const unsigned short* __restrict__ hs,
                                             const unsigned short* __restrict__ wqf,
                                             const unsigned short* __restrict__ wkTf,
                                             const unsigned short* __restrict__ wvf,
                                             float* __restrict__ out) {
    __shared__ __align__(16) unsigned short hsl[128][136];
    __shared__ __align__(16) unsigned short ub[8][136];
    __shared__ float qk[8][132];
    __shared__ float attl[8][20];
    __shared__ __align__(16) unsigned short svb[8][136];

    int tid = threadIdx.x, w = tid >> 6, L = tid & 63;
    int l15 = L & 15, q = L >> 4;
    int n0 = blockIdx.x * 8;

    {
        const unsigned short* src = hs + ((size_t)(n0 + (tid >> 4)) * L_ + (tid & 15)) * D_;
#pragma unroll
        for (int c = 0; c < 128; c += 8)
            *(ushort8*)&hsl[tid][c] = *(const ushort8*)(src + c);
    }
    __syncthreads();

    // u[s] = last[s] @ wq   (rows duplicated l15&7; C rows >= 8 dropped)
    {
        bf16x8 af[4];
#pragma unroll
        for (int kt = 0; kt < 4; ++kt)
            af[kt] = *(const bf16x8*)&hsl[(l15 & 7) * 16 + 15][kt * 32 + q * 8];
#pragma unroll
        for (int i = 0; i < 4; ++i) {
            int tl = 4 * w + i;
            f32x4 acc = (f32x4){0.f, 0.f, 0.f, 0.f};
#pragma unroll
            for (int kt = 0; kt < 4; ++kt)
                acc = __builtin_amdgcn_mfma_f32_16x16x32_bf16(
                    af[kt], *(const bf16x8*)(wqf + (size_t)((tl * 4 + kt) * 64 + L) * 8), acc, 0, 0, 0);
#pragma unroll
            for (int j = 0; j < 4; ++j) {
                int s = q * 4 + j;
                if (s < 8) ub[s][tl * 16 + l15] = f2bf(acc[j]);
            }
        }
    }
    __syncthreads();

    // qk[s] = u[s] @ wk^T
    {
        bf16x8 af[4];
#pragma unroll
        for (int kt = 0; kt < 4; ++kt)
            af[kt] = *(const bf16x8*)&ub[l15 & 7][kt * 32 + q * 8];
#pragma unroll
        for (int i = 0; i < 4; ++i) {
            int tl = 4 * w + i;
            f32x4 acc = (f32x4){0.f, 0.f, 0.f, 0.f};
#pragma unroll
            for (int kt = 0; kt < 4; ++kt)
                acc = __builtin_amdgcn_mfma_f32_16x16x32_bf16(
                    af[kt], *(const bf16x8*)(wkTf + (size_t)((tl * 4 + kt) * 64 + L) * 8), acc, 0, 0, 0);
#pragma unroll
            for (int j = 0; j < 4; ++j) {
                int s = q * 4 + j;
                if (s < 8) qk[s][tl * 16 + l15] = acc[j];
            }
        }
    }
    __syncthreads();

    // att[s][l] = hs[s][l][:] . qk[s][:]
    {
        int s = tid >> 4, l = tid & 15;
        const unsigned short* hr = &hsl[s * 16 + l][0];
        float a = 0.f;
        for (int k = 0; k < 128; k += 2) {
            unsigned pp = *(const unsigned*)(hr + k);
            float2 qq = *(const float2*)&qk[s][k];
            a += bf2f(pp & 0xffffu) * qq.x + bf2f(pp >> 16) * qq.y;
        }
        attl[s][l] = a;
    }
    __syncthreads();

    // svec[s][d] = sum_l att[s][l] * hs[s][l][d]
    {
        int s = tid >> 4, d0 = (tid & 15) * 8;
        float v[8];
#pragma unroll
        for (int j = 0; j < 8; ++j) v[j] = 0.f;
        for (int l = 0; l < 16; ++l) {
            float a = attl[s][l];
            ushort8 hh = *(const ushort8*)&hsl[s * 16 + l][d0];
#pragma unroll
            for (int j = 0; j < 8; ++j) v[j] += a * bf2f((unsigned)(unsigned short)hh[j]);
        }
        ushort8 t8;
#pragma unroll
        for (int j = 0; j < 8; ++j) t8[j] = f2bf(v[j]);
        *(ushort8*)&svb[s][d0] = t8;
    }
    __syncthreads();

    // ctx = svec @ wv
    {
        bf16x8 af[4];
#pragma unroll
        for (int kt = 0; kt < 4; ++kt)
            af[kt] = *(const bf16x8*)&svb[l15 & 7][kt * 32 + q * 8];
#pragma unroll
        for (int i = 0; i < 4; ++i) {
            int tl = 4 * w + i;
            f32x4 acc = (f32x4){0.f, 0.f, 0.f, 0.f};
#pragma unroll
            for (int kt = 0; kt < 4; ++kt)
                acc = __builtin_amdgcn_mfma_f32_16x16x32_bf16(
                    af[kt], *(const bf16x8*)(wvf + (size_t)((tl * 4 + kt) * 64 + L) * 8), acc, 0, 0, 0);
#pragma unroll
            for (int j = 0; j < 4; ++j) {
                int s = q * 4 + j;
                if (s < 8) out[(size_t)(n0 + s) * D_ + tl * 16 + l15] = acc[j];
            }
        }
    }
}

// ---------------------------------------------------------------------------
extern "C" void kernel_launch(void* const* d_in, const int* in_sizes, int n_in,
                              void* d_out, int out_size, void* d_ws, size_t ws_size,
                              hipStream_t stream) {
    const float* inputs = (const float*)d_in[0];
    const float* W_in   = (const float*)d_in[1];
    const float* W_rec  = (const float*)d_in[2];
    const float* b_in   = (const float*)d_in[3];
    const float* b_rec  = (const float*)d_in[4];
    const float* wq     = (const float*)d_in[5];
    const float* wk     = (const float*)d_in[6];
    const float* wvp    = (const float*)d_in[7];
    const int* paths    = (const int*)d_in[8];
    const int* idx      = (const int*)d_in[9];
    const int* seqs     = (const int*)d_in[10];
    int J = in_sizes[8];

    // ws layout (bytes), total = 151,420,928 (~144.4 MiB)
    const size_t off_pt   = 0;
    const size_t off_WfR  = off_pt   + (size_t)P_ * L_ * 4;        // 131072
    const size_t off_WfI  = off_WfR  + (size_t)24 * 256 * 16;      // +98304
    const size_t off_wqf  = off_WfI  + (size_t)24 * 256 * 16;      // +98304
    const size_t off_wkTf = off_wqf  + (size_t)8 * 256 * 16;       // +32768
    const size_t off_wvf  = off_wkTf + (size_t)8 * 256 * 16;       // +32768
    const size_t off_G2   = off_wvf  + (size_t)8 * 256 * 16;       // +32768
    const size_t off_hs   = off_G2   + (size_t)B_ * E_ * 128 * 8;  // +16777216
    char* ws = (char*)d_ws;
    int* pt             = (int*)(ws + off_pt);
    unsigned short* WfR  = (unsigned short*)(ws + off_WfR);
    unsigned short* WfI  = (unsigned short*)(ws + off_WfI);
    unsigned short* wqf  = (unsigned short*)(ws + off_wqf);
    unsigned short* wkTf = (unsigned short*)(ws + off_wkTf);
    unsigned short* wvf  = (unsigned short*)(ws + off_wvf);
    unsigned short* G2   = (unsigned short*)(ws + off_G2);
    unsigned short* hs   = (unsigned short*)(ws + off_hs);
    float* out = (float*)d_out;

    int scat_blocks = (J + 255) / 256;
    k_prep<<<dim3(200), dim3(256), 0, stream>>>(W_rec, W_in, wq, wk, wvp, pt,
                                                WfR, WfI, wqf, wkTf, wvf);
    k_G<<<dim3(1024 + scat_blocks), dim3(256), 0, stream>>>(inputs, WfI, b_in, G2,
                                                            paths, idx, seqs, J, pt);
    k_rec<<<dim3(B_ * P_ / 16), dim3(256), 0, stream>>>(WfR, b_rec, b_in, G2, pt, hs);
    k_att<<<dim3(B_ * P_ / 8), dim3(128), 0, stream>>>(hs, wqf, wkTf, wvf, out);
}

// Round 6
// 223.338 us; speedup vs baseline: 5.7619x; 1.2062x over previous
//
#include <hip/hip_runtime.h>
#include <hip/hip_bf16.h>
#include <cstddef>

#define P_ 2048
#define B_ 16
#define E_ 1024
#define D_ 128
#define L_ 16
#define TD_ 384

typedef __bf16 bf16x8 __attribute__((ext_vector_type(8)));
typedef float  f32x4  __attribute__((ext_vector_type(4)));
typedef unsigned short ushort8 __attribute__((ext_vector_type(8)));

__device__ __forceinline__ unsigned short f2bf(float x) {
    union { float f; unsigned u; } v; v.f = x;
    unsigned r = v.u + 0x7fff + ((v.u >> 16) & 1);   // RNE
    return (unsigned short)(r >> 16);
}
__device__ __forceinline__ float bf2f(unsigned x) {
    union { unsigned u; float f; } v; v.u = x << 16;
    return v.f;
}

// ---- B-fragment swizzle: frag[(tile*4+kt)*64+lane][j] = src[k0+j][tile*16+(lane&15)]
__device__ __forceinline__ void wf_body(const float* __restrict__ src,
                                        unsigned short* __restrict__ dst, int g, int N) {
    int lane = g & 63, kt = (g >> 6) & 3, tile = g >> 8;
    int k0 = kt * 32 + (lane >> 4) * 8;
    int c = tile * 16 + (lane & 15);
#pragma unroll
    for (int j = 0; j < 8; ++j)
        dst[(size_t)g * 8 + j] = f2bf(src[(size_t)(k0 + j) * N + c]);
}

// ---- k_prep: pt init + weight swizzles + M = wq@wk^T (fp32), one launch ---
// blocks: [0,128) pt | [128,152) WfR | [152,176) WfI | [176,184) wvf | [184,248) M
__global__ __launch_bounds__(256) void k_prep(const float* __restrict__ W_rec,
                                              const float* __restrict__ W_in,
                                              const float* __restrict__ wq,
                                              const float* __restrict__ wk,
                                              const float* __restrict__ wv,
                                              int* __restrict__ pt,
                                              unsigned short* __restrict__ WfR,
                                              unsigned short* __restrict__ WfI,
                                              unsigned short* __restrict__ wvf,
                                              float* __restrict__ M) {
    __shared__ float wk_lds[128 * 129];
    __shared__ float wq_row2[2][128];
    int blk = blockIdx.x, tid = threadIdx.x;
    if      (blk < 128) { pt[blk * 256 + tid] = -1; return; }
    else if (blk < 152) { wf_body(W_rec, WfR, (blk - 128) * 256 + tid, TD_); return; }
    else if (blk < 176) { wf_body(W_in,  WfI, (blk - 152) * 256 + tid, TD_); return; }
    else if (blk < 184) { wf_body(wv,    wvf, (blk - 176) * 256 + tid, 128); return; }
    // M rows j0, j0+1:  M[j][d] = sum_k wq[j][k] * wk[d][k]
    int j0 = (blk - 184) * 2;
    int d = tid & 127, half = tid >> 7;
    for (int r = half * 64; r < half * 64 + 64; ++r)
        wk_lds[r * 129 + d] = wk[r * 128 + d];
    wq_row2[half][d] = wq[(j0 + half) * 128 + d];
    __syncthreads();
    float acc = 0.f;
    for (int k = 0; k < 128; ++k) acc += wq_row2[half][k] * wk_lds[d * 129 + k];
    M[(j0 + half) * 128 + d] = acc;
}

// ---- k_G: G2[row][d][4]={z,r,h,pad} via MFMA; tails: pt scatter + Mf swizzle
__global__ __launch_bounds__(256) void k_G(const float* __restrict__ inputs,
                                           const unsigned short* __restrict__ WfI,
                                           const float* __restrict__ b_in,
                                           unsigned short* __restrict__ G2,
                                           const int* __restrict__ paths,
                                           const int* __restrict__ idx,
                                           const int* __restrict__ seqs, int J, int scatB,
                                           int* __restrict__ pt,
                                           const float* __restrict__ M,
                                           unsigned short* __restrict__ Mf) {
    if (blockIdx.x >= 1024) {
        int tb = blockIdx.x - 1024;
        if (tb < scatB) {
            int j = tb * 256 + threadIdx.x;
            if (j < J) pt[idx[j] * L_ + seqs[j]] = paths[j];
        } else {
            wf_body(M, Mf, (tb - scatB) * 256 + threadIdx.x, 128);   // 8 blocks
        }
        return;
    }
    __shared__ __align__(16) unsigned short a_lds[16][136];
    int tid = threadIdx.x, w = tid >> 6, L = tid & 63;
    int l15 = L & 15, q = L >> 4;
    int row0 = blockIdx.x * 16;
    {
        int r = tid >> 4, c = (tid & 15) * 8;
        const float4* p = (const float4*)(inputs + (size_t)(row0 + r) * 128 + c);
        float4 v0 = p[0], v1 = p[1];
        ushort8 t8;
        t8[0] = f2bf(v0.x); t8[1] = f2bf(v0.y); t8[2] = f2bf(v0.z); t8[3] = f2bf(v0.w);
        t8[4] = f2bf(v1.x); t8[5] = f2bf(v1.y); t8[6] = f2bf(v1.z); t8[7] = f2bf(v1.w);
        *(ushort8*)&a_lds[r][c] = t8;
    }
    __syncthreads();
    bf16x8 af[4];
#pragma unroll
    for (int kt = 0; kt < 4; ++kt)
        af[kt] = *(const bf16x8*)&a_lds[l15][kt * 32 + q * 8];
#pragma unroll
    for (int ct = 0; ct < 6; ++ct) {
        int tl = 6 * w + ct;
        f32x4 acc = (f32x4){0.f, 0.f, 0.f, 0.f};
#pragma unroll
        for (int kt = 0; kt < 4; ++kt)
            acc = __builtin_amdgcn_mfma_f32_16x16x32_bf16(
                af[kt], *(const bf16x8*)(WfI + (size_t)((tl * 4 + kt) * 64 + L) * 8), acc, 0, 0, 0);
        int g  = tl >> 3;
        int dd = (tl & 7) * 16 + l15;
        float bia = b_in[tl * 16 + l15];
#pragma unroll
        for (int j = 0; j < 4; ++j) {
            int r = q * 4 + j;
            G2[((size_t)(row0 + r) * 128 + dd) * 4 + g] = f2bf(acc[j] + bia);
        }
    }
}

// ---- fused GRU recurrence + attention, 16 seqs/block, hs never leaves LDS -
__global__ __launch_bounds__(256) void k_rec(const unsigned short* __restrict__ WfR,
                                             const float* __restrict__ b_rec,
                                             const float* __restrict__ b_in,
                                             const unsigned short* __restrict__ G2,
                                             const int* __restrict__ pt,
                                             const unsigned short* __restrict__ Mf,
                                             const unsigned short* __restrict__ wvf,
                                             float* __restrict__ out) {
    __shared__ __align__(16) unsigned short hsl[16][16][136];   // [t][seq][d] 69632 B
    __shared__ __align__(16) unsigned short qkb[16][136];       // 4352 B
    __shared__ __align__(16) unsigned short svb[16][136];       // 4352 B
    __shared__ float attl[16][20];                              // 1280 B
    __shared__ int pt_lds[16][16];                              // 1024 B

    int tid = threadIdx.x, w = tid >> 6, L = tid & 63;
    int l15 = L & 15, q = L >> 4;
    int c0 = 32 * w + l15, c1 = c0 + 16;
    int n0 = blockIdx.x * 16;
    int b  = n0 >> 11;
    int p0 = n0 & (P_ - 1);

    const int tiles[6] = {2 * w, 2 * w + 1, 8 + 2 * w, 9 + 2 * w, 16 + 2 * w, 17 + 2 * w};
    bf16x8 bfrag[6][4];
#pragma unroll
    for (int ct = 0; ct < 6; ++ct)
#pragma unroll
        for (int kt = 0; kt < 4; ++kt)
            bfrag[ct][kt] = *(const bf16x8*)(WfR + (size_t)((tiles[ct] * 4 + kt) * 64 + L) * 8);

    pt_lds[tid >> 4][tid & 15] = pt[p0 * L_ + tid];

    float bz0 = b_in[c0], br0 = b_in[128 + c0], bh0 = b_in[256 + c0];
    float bz1 = b_in[c1], br1 = b_in[128 + c1], bh1 = b_in[256 + c1];
    float rz0 = b_rec[c0], rr0 = b_rec[128 + c0], rh0 = b_rec[256 + c0];
    float rz1 = b_rec[c1], rr1 = b_rec[128 + c1], rh1 = b_rec[256 + c1];
    float h_reg[8];
#pragma unroll
    for (int i = 0; i < 8; ++i) h_reg[i] = 0.f;
    __syncthreads();

    const unsigned short* g2b = G2 + (size_t)b * E_ * 512;

    uint2 cur[4][2];
#pragma unroll
    for (int j = 0; j < 4; ++j) {
        int e = pt_lds[q * 4 + j][0];
        cur[j][0] = make_uint2(0u, 0u); cur[j][1] = make_uint2(0u, 0u);
        if (e >= 0) {
            const unsigned short* gp = g2b + (size_t)e * 512;
            cur[j][0] = *(const uint2*)(gp + c0 * 4);
            cur[j][1] = *(const uint2*)(gp + c1 * 4);
        }
    }

    for (int t = 0; t < L_; ++t) {
        // prefetch next step's G rows
        uint2 nxt[4][2];
#pragma unroll
        for (int j = 0; j < 4; ++j) { nxt[j][0] = make_uint2(0u, 0u); nxt[j][1] = make_uint2(0u, 0u); }
        if (t < 15) {
#pragma unroll
            for (int j = 0; j < 4; ++j) {
                int e = pt_lds[q * 4 + j][t + 1];
                if (e >= 0) {
                    const unsigned short* gp = g2b + (size_t)e * 512;
                    nxt[j][0] = *(const uint2*)(gp + c0 * 4);
                    nxt[j][1] = *(const uint2*)(gp + c1 * 4);
                }
            }
        }

        // MFMA from previous step's h (t==0: h==0 -> all-zero gates, skip)
        f32x4 acc[6];
#pragma unroll
        for (int ct = 0; ct < 6; ++ct) acc[ct] = (f32x4){0.f, 0.f, 0.f, 0.f};
        if (t > 0) {
            bf16x8 af[4];
#pragma unroll
            for (int kt = 0; kt < 4; ++kt)
                af[kt] = *(const bf16x8*)&hsl[t - 1][l15][kt * 32 + q * 8];
#pragma unroll
            for (int ct = 0; ct < 6; ++ct)
#pragma unroll
                for (int kt = 0; kt < 4; ++kt)
                    acc[ct] = __builtin_amdgcn_mfma_f32_16x16x32_bf16(af[kt], bfrag[ct][kt], acc[ct], 0, 0, 0);
        }

        // epilogue straight from acc registers; h history stays in LDS
#pragma unroll
        for (int j = 0; j < 4; ++j) {
            int row = q * 4 + j;
            int e = pt_lds[row][t];
#pragma unroll
            for (int half = 0; half < 2; ++half) {
                float xz, xr, xh;
                if (e >= 0) {
                    unsigned a = cur[j][half].x, bb = cur[j][half].y;
                    xz = bf2f(a & 0xffffu); xr = bf2f(a >> 16); xh = bf2f(bb & 0xffffu);
                } else {
                    xz = half ? bz1 : bz0; xr = half ? br1 : br0; xh = half ? bh1 : bh0;
                }
                float az = acc[half][j]     + (half ? rz1 : rz0);
                float ar = acc[2 + half][j] + (half ? rr1 : rr0);
                float ah = acc[4 + half][j] + (half ? rh1 : rh0);
                float z   = __builtin_amdgcn_rcpf(1.f + __expf(-(xz + az)));
                float rg  = __builtin_amdgcn_rcpf(1.f + __expf(-(xr + ar)));
                float pre = xh + rg * ah;
                float hc  = 1.f - 2.f * __builtin_amdgcn_rcpf(__expf(2.f * pre) + 1.f);
                float hn  = z * h_reg[j * 2 + half] + (1.f - z) * hc;
                h_reg[j * 2 + half] = hn;
                hsl[t][row][half ? c1 : c0] = f2bf(hn);
                cur[j][half] = nxt[j][half];
            }
        }
        __syncthreads();
    }

    // ===== attention phase (hsl resident) =====
    // qk[s] = last[s] @ M   (A rows = 16 seqs exactly)
    {
        bf16x8 af[4];
#pragma unroll
        for (int kt = 0; kt < 4; ++kt)
            af[kt] = *(const bf16x8*)&hsl[15][l15][kt * 32 + q * 8];
#pragma unroll
        for (int i = 0; i < 2; ++i) {
            int tl = 2 * w + i;
            f32x4 acc = (f32x4){0.f, 0.f, 0.f, 0.f};
#pragma unroll
            for (int kt = 0; kt < 4; ++kt)
                acc = __builtin_amdgcn_mfma_f32_16x16x32_bf16(
                    af[kt], *(const bf16x8*)(Mf + (size_t)((tl * 4 + kt) * 64 + L) * 8), acc, 0, 0, 0);
#pragma unroll
            for (int j = 0; j < 4; ++j)
                qkb[q * 4 + j][tl * 16 + l15] = f2bf(acc[j]);
        }
    }
    __syncthreads();

    // att[s][l] = hs[s][l][:] . qk[s][:]   (thread: s = tid&15, l = tid>>4)
    {
        int s = tid & 15, l = tid >> 4;
        const unsigned short* hr = &hsl[l][s][0];
        const unsigned short* qr = &qkb[s][0];
        float a = 0.f;
        for (int k = 0; k < 128; k += 2) {
            unsigned hh = *(const unsigned*)(hr + k);
            unsigned qq = *(const unsigned*)(qr + k);
            a += bf2f(hh & 0xffffu) * bf2f(qq & 0xffffu) + bf2f(hh >> 16) * bf2f(qq >> 16);
        }
        attl[s][l] = a;
    }
    __syncthreads();

    // svec[s][d] = sum_l att[s][l] * hs[s][l][d]
    {
        int s = tid >> 4, d0 = (tid & 15) * 8;
        float v[8];
#pragma unroll
        for (int j = 0; j < 8; ++j) v[j] = 0.f;
        for (int l = 0; l < 16; ++l) {
            float a = attl[s][l];
            ushort8 hh = *(const ushort8*)&hsl[l][s][d0];
#pragma unroll
            for (int j = 0; j < 8; ++j) v[j] += a * bf2f((unsigned)(unsigned short)hh[j]);
        }
        ushort8 t8;
#pragma unroll
        for (int j = 0; j < 8; ++j) t8[j] = f2bf(v[j]);
        *(ushort8*)&svb[s][d0] = t8;
    }
    __syncthreads();

    // ctx = svec @ wv -> out
    {
        bf16x8 af[4];
#pragma unroll
        for (int kt = 0; kt < 4; ++kt)
            af[kt] = *(const bf16x8*)&svb[l15][kt * 32 + q * 8];
#pragma unroll
        for (int i = 0; i < 2; ++i) {
            int tl = 2 * w + i;
            f32x4 acc = (f32x4){0.f, 0.f, 0.f, 0.f};
#pragma unroll
            for (int kt = 0; kt < 4; ++kt)
                acc = __builtin_amdgcn_mfma_f32_16x16x32_bf16(
                    af[kt], *(const bf16x8*)(wvf + (size_t)((tl * 4 + kt) * 64 + L) * 8), acc, 0, 0, 0);
#pragma unroll
            for (int j = 0; j < 4; ++j)
                out[(size_t)(n0 + q * 4 + j) * D_ + tl * 16 + l15] = acc[j];
        }
    }
}

// ---------------------------------------------------------------------------
extern "C" void kernel_launch(void* const* d_in, const int* in_sizes, int n_in,
                              void* d_out, int out_size, void* d_ws, size_t ws_size,
                              hipStream_t stream) {
    const float* inputs = (const float*)d_in[0];
    const float* W_in   = (const float*)d_in[1];
    const float* W_rec  = (const float*)d_in[2];
    const float* b_in   = (const float*)d_in[3];
    const float* b_rec  = (const float*)d_in[4];
    const float* wq     = (const float*)d_in[5];
    const float* wk     = (const float*)d_in[6];
    const float* wvp    = (const float*)d_in[7];
    const int* paths    = (const int*)d_in[8];
    const int* idx      = (const int*)d_in[9];
    const int* seqs     = (const int*)d_in[10];
    int J = in_sizes[8];

    // ws layout (bytes): total 17,235,968 (~16.4 MiB)
    const size_t off_pt  = 0;
    const size_t off_WfR = off_pt  + (size_t)P_ * L_ * 4;        // 131072
    const size_t off_WfI = off_WfR + (size_t)24 * 256 * 16;      // +98304
    const size_t off_Mf  = off_WfI + (size_t)24 * 256 * 16;      // +98304
    const size_t off_wvf = off_Mf  + (size_t)8 * 256 * 16;       // +32768
    const size_t off_M   = off_wvf + (size_t)8 * 256 * 16;       // +32768
    const size_t off_G2  = off_M   + (size_t)128 * 128 * 4;      // +65536
    char* ws = (char*)d_ws;
    int* pt             = (int*)(ws + off_pt);
    unsigned short* WfR = (unsigned short*)(ws + off_WfR);
    unsigned short* WfI = (unsigned short*)(ws + off_WfI);
    unsigned short* Mf  = (unsigned short*)(ws + off_Mf);
    unsigned short* wvf = (unsigned short*)(ws + off_wvf);
    float* M            = (float*)(ws + off_M);
    unsigned short* G2  = (unsigned short*)(ws + off_G2);
    float* out = (float*)d_out;

    int scatB = (J + 255) / 256;
    k_prep<<<dim3(248), dim3(256), 0, stream>>>(W_rec, W_in, wq, wk, wvp, pt,
                                                WfR, WfI, wvf, M);
    k_G<<<dim3(1024 + scatB + 8), dim3(256), 0, stream>>>(inputs, WfI, b_in, G2,
                                                          paths, idx, seqs, J, scatB,
                                                          pt, M, Mf);
    k_rec<<<dim3(B_ * P_ / 16), dim3(256), 0, stream>>>(WfR, b_rec, b_in, G2, pt,
                                                        Mf, wvf, out);
}

// Round 8
// 208.368 us; speedup vs baseline: 6.1759x; 1.0718x over previous
//
#include <hip/hip_runtime.h>
#include <hip/hip_bf16.h>
#include <cstddef>

#define P_ 2048
#define B_ 16
#define E_ 1024
#define D_ 128
#define L_ 16
#define TD_ 384

typedef _Float16 f16x2 __attribute__((ext_vector_type(2)));
typedef _Float16 f16x8 __attribute__((ext_vector_type(8)));
typedef float    f32x4 __attribute__((ext_vector_type(4)));

__device__ __forceinline__ unsigned short f2h(float x) {
    _Float16 h = (_Float16)x;
    return __builtin_bit_cast(unsigned short, h);
}
// packed cvt f32x2 -> f16x2, returned as a 32-bit word
__device__ __forceinline__ unsigned pk2(float a, float b) {
    return __builtin_bit_cast(unsigned, __builtin_amdgcn_cvt_pkrtz(a, b));
}

// ---- B-fragment swizzle (f16): frag[(tile*4+kt)*64+lane][j] = src[k0+j][tile*16+(lane&15)]
__device__ __forceinline__ void wf16(const float* __restrict__ src,
                                     unsigned short* __restrict__ dst, int g, int N) {
    int lane = g & 63, kt = (g >> 6) & 3, tile = g >> 8;
    int k0 = kt * 32 + (lane >> 4) * 8;
    int c = tile * 16 + (lane & 15);
#pragma unroll
    for (int j = 0; j < 8; ++j)
        dst[(size_t)g * 8 + j] = f2h(src[(size_t)(k0 + j) * N + c]);
}

// ---- k_prep: pt init + weight swizzles + M = wq@wk^T (fp32) ---------------
// blocks: [0,128) pt | [128,152) WfR | [152,176) WfI | [176,184) wvf | [184,248) M
__global__ __launch_bounds__(256) void k_prep(const float* __restrict__ W_rec,
                                              const float* __restrict__ W_in,
                                              const float* __restrict__ wq,
                                              const float* __restrict__ wk,
                                              const float* __restrict__ wv,
                                              int* __restrict__ pt,
                                              unsigned short* __restrict__ WfR,
                                              unsigned short* __restrict__ WfI,
                                              unsigned short* __restrict__ wvf,
                                              float* __restrict__ M) {
    __shared__ float wk_lds[128 * 129];
    __shared__ float wq_row2[2][128];
    int blk = blockIdx.x, tid = threadIdx.x;
    if      (blk < 128) { pt[blk * 256 + tid] = -1; return; }
    else if (blk < 152) { wf16(W_rec, WfR, (blk - 128) * 256 + tid, TD_); return; }
    else if (blk < 176) { wf16(W_in,  WfI, (blk - 152) * 256 + tid, TD_); return; }
    else if (blk < 184) { wf16(wv,    wvf, (blk - 176) * 256 + tid, 128); return; }
    int j0 = (blk - 184) * 2;
    int d = tid & 127, half = tid >> 7;
    for (int r = half * 64; r < half * 64 + 64; ++r)
        wk_lds[r * 129 + d] = wk[r * 128 + d];
    wq_row2[half][d] = wq[(j0 + half) * 128 + d];
    __syncthreads();
    float acc = 0.f;
    for (int k = 0; k < 128; ++k) acc += wq_row2[half][k] * wk_lds[d * 129 + k];
    M[(j0 + half) * 128 + d] = acc;
}

// ---- k_G: G2[row][d][4]={z,r,h,pad} (f16) via MFMA; tails: scatter + Mf ---
__global__ __launch_bounds__(256) void k_G(const float* __restrict__ inputs,
                                           const unsigned short* __restrict__ WfI,
                                           const float* __restrict__ b_in,
                                           unsigned short* __restrict__ G2,
                                           const int* __restrict__ paths,
                                           const int* __restrict__ idx,
                                           const int* __restrict__ seqs, int J, int scatB,
                                           int* __restrict__ pt,
                                           const float* __restrict__ M,
                                           unsigned short* __restrict__ Mf) {
    if (blockIdx.x >= 1024) {
        int tb = blockIdx.x - 1024;
        if (tb < scatB) {
            int j = tb * 256 + threadIdx.x;
            if (j < J) pt[idx[j] * L_ + seqs[j]] = paths[j];
        } else {
            wf16(M, Mf, (tb - scatB) * 256 + threadIdx.x, 128);
        }
        return;
    }
    __shared__ __align__(16) unsigned short a_lds[16][136];
    int tid = threadIdx.x, w = tid >> 6, L = tid & 63;
    int l15 = L & 15, q = L >> 4;
    int row0 = blockIdx.x * 16;
    {
        int r = tid >> 4, c = (tid & 15) * 8;
        const float4* p = (const float4*)(inputs + (size_t)(row0 + r) * 128 + c);
        float4 v0 = p[0], v1 = p[1];
        uint4 st;
        st.x = pk2(v0.x, v0.y); st.y = pk2(v0.z, v0.w);
        st.z = pk2(v1.x, v1.y); st.w = pk2(v1.z, v1.w);
        *(uint4*)&a_lds[r][c] = st;
    }
    __syncthreads();
    f16x8 af[4];
#pragma unroll
    for (int kt = 0; kt < 4; ++kt)
        af[kt] = *(const f16x8*)&a_lds[l15][kt * 32 + q * 8];
#pragma unroll
    for (int ct = 0; ct < 6; ++ct) {
        int tl = 6 * w + ct;
        f32x4 acc = (f32x4){0.f, 0.f, 0.f, 0.f};
#pragma unroll
        for (int kt = 0; kt < 4; ++kt)
            acc = __builtin_amdgcn_mfma_f32_16x16x32_f16(
                af[kt], *(const f16x8*)(WfI + (size_t)((tl * 4 + kt) * 64 + L) * 8), acc, 0, 0, 0);
        int g  = tl >> 3;
        int dd = (tl & 7) * 16 + l15;
        float bia = b_in[tl * 16 + l15];
#pragma unroll
        for (int j = 0; j < 4; ++j) {
            int r = q * 4 + j;
            G2[((size_t)(row0 + r) * 128 + dd) * 4 + g] = f2h(acc[j] + bia);
        }
    }
}

// ---- fused GRU + attention: 512 threads (8 waves), 16 seqs/block ----------
// wave w owns gate cols [16w,16w+16) via tiles {w (z), 8+w (r), 16+w (h)}.
// Lane (q,l15): col c=16w+l15, rows q*4..q*4+3.
__global__ __launch_bounds__(512, 4) void k_rec(const unsigned short* __restrict__ WfR,
                                                const float* __restrict__ b_rec,
                                                const float* __restrict__ b_in,
                                                const unsigned short* __restrict__ G2,
                                                const int* __restrict__ pt,
                                                const unsigned short* __restrict__ Mf,
                                                const unsigned short* __restrict__ wvf,
                                                float* __restrict__ out) {
    __shared__ __align__(16) unsigned short hsl[16][16][136];   // 69632 B
    __shared__ __align__(16) unsigned short qkb[16][136];       // 4352 B
    __shared__ __align__(16) unsigned short svb[16][136];       // 4352 B
    __shared__ float attl[16][20];                              // 1280 B
    __shared__ int pt_lds[16][16];                              // 1024 B

    int tid = threadIdx.x, w = tid >> 6, L = tid & 63;
    int l15 = L & 15, q = L >> 4;
    int c = 16 * w + l15;
    int n0 = blockIdx.x * 16;
    int b  = n0 >> 11;
    int p0 = n0 & (P_ - 1);

    // B-fragments: 3 tiles (z,r,h for this wave's 16 cols), 48 VGPRs
    f16x8 bfrag[3][4];
#pragma unroll
    for (int g = 0; g < 3; ++g)
#pragma unroll
        for (int kt = 0; kt < 4; ++kt)
            bfrag[g][kt] = *(const f16x8*)(WfR + (size_t)(((g * 8 + w) * 4 + kt) * 64 + L) * 8);

    if (tid < 256) pt_lds[tid >> 4][tid & 15] = pt[p0 * L_ + tid];

    float bz = b_in[c], br = b_in[128 + c], bh = b_in[256 + c];
    float rz = b_rec[c], rr = b_rec[128 + c], rh = b_rec[256 + c];
    float h_reg[4];
#pragma unroll
    for (int i = 0; i < 4; ++i) h_reg[i] = 0.f;
    __syncthreads();

    const unsigned short* g2b = G2 + (size_t)b * E_ * 512 + (size_t)c * 4;

    uint2 cur[4];
#pragma unroll
    for (int j = 0; j < 4; ++j) {
        int e = pt_lds[q * 4 + j][0];
        cur[j] = make_uint2(0u, 0u);
        if (e >= 0) cur[j] = *(const uint2*)(g2b + (size_t)e * 512);
    }

    for (int t = 0; t < L_; ++t) {
        // prefetch next step's G rows
        uint2 nxt[4];
#pragma unroll
        for (int j = 0; j < 4; ++j) nxt[j] = make_uint2(0u, 0u);
        if (t < 15) {
#pragma unroll
            for (int j = 0; j < 4; ++j) {
                int e = pt_lds[q * 4 + j][t + 1];
                if (e >= 0) nxt[j] = *(const uint2*)(g2b + (size_t)e * 512);
            }
        }

        // MFMA from previous step's h (t==0: h==0 -> zero gates)
        f32x4 acc[3];
#pragma unroll
        for (int g = 0; g < 3; ++g) acc[g] = (f32x4){0.f, 0.f, 0.f, 0.f};
        if (t > 0) {
            f16x8 af[4];
#pragma unroll
            for (int kt = 0; kt < 4; ++kt)
                af[kt] = *(const f16x8*)&hsl[t - 1][l15][kt * 32 + q * 8];
#pragma unroll
            for (int g = 0; g < 3; ++g)
#pragma unroll
                for (int kt = 0; kt < 4; ++kt)
                    acc[g] = __builtin_amdgcn_mfma_f32_16x16x32_f16(af[kt], bfrag[g][kt], acc[g], 0, 0, 0);
        }

        // epilogue: 4 elements (rows q*4..q*4+3, col c)
#pragma unroll
        for (int j = 0; j < 4; ++j) {
            int row = q * 4 + j;
            int e = pt_lds[row][t];
            float xz, xr, xh;
            if (e >= 0) {
                f16x2 zr = __builtin_bit_cast(f16x2, cur[j].x);
                f16x2 hp = __builtin_bit_cast(f16x2, cur[j].y);
                xz = (float)zr[0]; xr = (float)zr[1]; xh = (float)hp[0];
            } else {
                xz = bz; xr = br; xh = bh;
            }
            float z   = __builtin_amdgcn_rcpf(1.f + __expf(-(xz + acc[0][j] + rz)));
            float rg  = __builtin_amdgcn_rcpf(1.f + __expf(-(xr + acc[1][j] + rr)));
            float pre = xh + rg * (acc[2][j] + rh);
            float hc  = 1.f - 2.f * __builtin_amdgcn_rcpf(__expf(2.f * pre) + 1.f);
            float hn  = hc + z * (h_reg[j] - hc);
            h_reg[j] = hn;
            hsl[t][row][c] = f2h(hn);
            cur[j] = nxt[j];
        }
        __syncthreads();
    }

    // ===== attention (hsl resident) =====
    // qk[s] = last[s] @ M : wave w computes cols [16w,16w+16)
    {
        f16x8 af[4];
#pragma unroll
        for (int kt = 0; kt < 4; ++kt)
            af[kt] = *(const f16x8*)&hsl[15][l15][kt * 32 + q * 8];
        f32x4 acc = (f32x4){0.f, 0.f, 0.f, 0.f};
#pragma unroll
        for (int kt = 0; kt < 4; ++kt)
            acc = __builtin_amdgcn_mfma_f32_16x16x32_f16(
                af[kt], *(const f16x8*)(Mf + (size_t)((w * 4 + kt) * 64 + L) * 8), acc, 0, 0, 0);
#pragma unroll
        for (int j = 0; j < 4; ++j)
            qkb[q * 4 + j][c] = f2h(acc[j]);
    }
    __syncthreads();

    // att[s][l] = hs[s][l][:] . qk[s][:]   (threads 0..255: s=tid&15, l=tid>>4)
    if (tid < 256) {
        int s = tid & 15, l = tid >> 4;
        const unsigned short* hr = &hsl[l][s][0];
        const unsigned short* qr = &qkb[s][0];
        float a = 0.f;
#pragma unroll
        for (int k = 0; k < 128; k += 2) {
            f16x2 hh = *(const f16x2*)(hr + k);
            f16x2 qq = *(const f16x2*)(qr + k);
            a += (float)hh[0] * (float)qq[0] + (float)hh[1] * (float)qq[1];
        }
        attl[s][l] = a;
    }
    __syncthreads();

    // svec[s][d] = sum_l att[s][l] * hs[s][l][d]  (s=tid>>5, 4 d's per thread)
    {
        int s = tid >> 5, d0 = (tid & 31) * 4;
        float v[4] = {0.f, 0.f, 0.f, 0.f};
#pragma unroll
        for (int l = 0; l < 16; ++l) {
            float a = attl[s][l];
            f16x2 h0 = *(const f16x2*)&hsl[l][s][d0];
            f16x2 h1 = *(const f16x2*)&hsl[l][s][d0 + 2];
            v[0] += a * (float)h0[0]; v[1] += a * (float)h0[1];
            v[2] += a * (float)h1[0]; v[3] += a * (float)h1[1];
        }
        uint2 st;
        st.x = pk2(v[0], v[1]); st.y = pk2(v[2], v[3]);
        *(uint2*)&svb[s][d0] = st;
    }
    __syncthreads();

    // ctx = svec @ wv -> out : wave w computes cols [16w,16w+16)
    {
        f16x8 af[4];
#pragma unroll
        for (int kt = 0; kt < 4; ++kt)
            af[kt] = *(const f16x8*)&svb[l15][kt * 32 + q * 8];
        f32x4 acc = (f32x4){0.f, 0.f, 0.f, 0.f};
#pragma unroll
        for (int kt = 0; kt < 4; ++kt)
            acc = __builtin_amdgcn_mfma_f32_16x16x32_f16(
                af[kt], *(const f16x8*)(wvf + (size_t)((w * 4 + kt) * 64 + L) * 8), acc, 0, 0, 0);
#pragma unroll
        for (int j = 0; j < 4; ++j)
            out[(size_t)(n0 + q * 4 + j) * D_ + c] = acc[j];
    }
}

// ---------------------------------------------------------------------------
extern "C" void kernel_launch(void* const* d_in, const int* in_sizes, int n_in,
                              void* d_out, int out_size, void* d_ws, size_t ws_size,
                              hipStream_t stream) {
    const float* inputs = (const float*)d_in[0];
    const float* W_in   = (const float*)d_in[1];
    const float* W_rec  = (const float*)d_in[2];
    const float* b_in   = (const float*)d_in[3];
    const float* b_rec  = (const float*)d_in[4];
    const float* wq     = (const float*)d_in[5];
    const float* wk     = (const float*)d_in[6];
    const float* wvp    = (const float*)d_in[7];
    const int* paths    = (const int*)d_in[8];
    const int* idx      = (const int*)d_in[9];
    const int* seqs     = (const int*)d_in[10];
    int J = in_sizes[8];

    // ws layout (bytes): total ~17.2 MiB
    const size_t off_pt  = 0;
    const size_t off_WfR = off_pt  + (size_t)P_ * L_ * 4;        // 131072
    const size_t off_WfI = off_WfR + (size_t)24 * 256 * 16;      // +98304
    const size_t off_Mf  = off_WfI + (size_t)24 * 256 * 16;      // +98304
    const size_t off_wvf = off_Mf  + (size_t)8 * 256 * 16;       // +32768
    const size_t off_M   = off_wvf + (size_t)8 * 256 * 16;       // +32768
    const size_t off_G2  = off_M   + (size_t)128 * 128 * 4;      // +65536
    char* ws = (char*)d_ws;
    int* pt             = (int*)(ws + off_pt);
    unsigned short* WfR = (unsigned short*)(ws + off_WfR);
    unsigned short* WfI = (unsigned short*)(ws + off_WfI);
    unsigned short* Mf  = (unsigned short*)(ws + off_Mf);
    unsigned short* wvf = (unsigned short*)(ws + off_wvf);
    float* M            = (float*)(ws + off_M);
    unsigned short* G2  = (unsigned short*)(ws + off_G2);
    float* out = (float*)d_out;

    int scatB = (J + 255) / 256;
    k_prep<<<dim3(248), dim3(256), 0, stream>>>(W_rec, W_in, wq, wk, wvp, pt,
                                                WfR, WfI, wvf, M);
    k_G<<<dim3(1024 + scatB + 8), dim3(256), 0, stream>>>(inputs, WfI, b_in, G2,
                                                          paths, idx, seqs, J, scatB,
                                                          pt, M, Mf);
    k_rec<<<dim3(B_ * P_ / 16), dim3(512), 0, stream>>>(WfR, b_rec, b_in, G2, pt,
                                                        Mf, wvf, out);
}

// Round 9
// 186.141 us; speedup vs baseline: 6.9133x; 1.1194x over previous
//
#include <hip/hip_runtime.h>
#include <hip/hip_bf16.h>
#include <cstddef>

#define P_ 2048
#define B_ 16
#define E_ 1024
#define D_ 128
#define L_ 16
#define TD_ 384

typedef _Float16 f16x2 __attribute__((ext_vector_type(2)));
typedef _Float16 f16x8 __attribute__((ext_vector_type(8)));
typedef float    f32x4 __attribute__((ext_vector_type(4)));

__device__ __forceinline__ unsigned short f2h(float x) {
    _Float16 h = (_Float16)x;
    return __builtin_bit_cast(unsigned short, h);
}
__device__ __forceinline__ unsigned pk2(float a, float b) {
    return __builtin_bit_cast(unsigned, __builtin_amdgcn_cvt_pkrtz(a, b));
}
__device__ __forceinline__ float lo16(unsigned u) {
    return (float)__builtin_bit_cast(f16x2, u)[0];
}
__device__ __forceinline__ float hi16(unsigned u) {
    return (float)__builtin_bit_cast(f16x2, u)[1];
}
__device__ __forceinline__ float dot2w(unsigned hu, unsigned qu, float c) {
#if __has_builtin(__builtin_amdgcn_fdot2)
    typedef __fp16 h2v __attribute__((ext_vector_type(2)));
    return __builtin_amdgcn_fdot2(__builtin_bit_cast(h2v, hu),
                                  __builtin_bit_cast(h2v, qu), c, false);
#else
    f16x2 h = __builtin_bit_cast(f16x2, hu), q = __builtin_bit_cast(f16x2, qu);
    return c + (float)h[0] * (float)q[0] + (float)h[1] * (float)q[1];
#endif
}

// ---- fragment swizzle (f16): frag[(tile*4+kt)*64+lane][j] = src[k0+j][tile*16+(lane&15)]
// Works as MFMA B-operand (B[k][n]) AND as A-operand (A[m][k] = src^T[m][k]).
__device__ __forceinline__ void wf16(const float* __restrict__ src,
                                     unsigned short* __restrict__ dst, int g, int N) {
    int lane = g & 63, kt = (g >> 6) & 3, tile = g >> 8;
    int k0 = kt * 32 + (lane >> 4) * 8;
    int c = tile * 16 + (lane & 15);
#pragma unroll
    for (int j = 0; j < 8; ++j)
        dst[(size_t)g * 8 + j] = f2h(src[(size_t)(k0 + j) * N + c]);
}

// ---- k_prep: pt init (to sentinel E_) + weight swizzles + M = wq@wk^T -----
// blocks: [0,128) pt | [128,152) WfR | [152,176) WfI | [176,184) wvf | [184,248) M
__global__ __launch_bounds__(256) void k_prep(const float* __restrict__ W_rec,
                                              const float* __restrict__ W_in,
                                              const float* __restrict__ wq,
                                              const float* __restrict__ wk,
                                              const float* __restrict__ wv,
                                              int* __restrict__ pt,
                                              unsigned short* __restrict__ WfR,
                                              unsigned short* __restrict__ WfI,
                                              unsigned short* __restrict__ wvf,
                                              float* __restrict__ M) {
    __shared__ float wk_lds[128 * 129];
    __shared__ float wq_row2[2][128];
    int blk = blockIdx.x, tid = threadIdx.x;
    if      (blk < 128) { pt[blk * 256 + tid] = E_; return; }
    else if (blk < 152) { wf16(W_rec, WfR, (blk - 128) * 256 + tid, TD_); return; }
    else if (blk < 176) { wf16(W_in,  WfI, (blk - 152) * 256 + tid, TD_); return; }
    else if (blk < 184) { wf16(wv,    wvf, (blk - 176) * 256 + tid, 128); return; }
    int j0 = (blk - 184) * 2;
    int d = tid & 127, half = tid >> 7;
    for (int r = half * 64; r < half * 64 + 64; ++r)
        wk_lds[r * 129 + d] = wk[r * 128 + d];
    wq_row2[half][d] = wq[(j0 + half) * 128 + d];
    __syncthreads();
    float acc = 0.f;
    for (int k = 0; k < 128; ++k) acc += wq_row2[half][k] * wk_lds[d * 129 + k];
    M[(j0 + half) * 128 + d] = acc;
}

// ---- k_G: G2[b*1025+e][col][4]={z+bz+rz, r+br+rr, xh+bh, pad} (f16) -------
// tails: pt scatter + Mf swizzle + sentinel rows (pure-bias)
__global__ __launch_bounds__(256) void k_G(const float* __restrict__ inputs,
                                           const unsigned short* __restrict__ WfI,
                                           const float* __restrict__ b_in,
                                           const float* __restrict__ b_rec,
                                           unsigned short* __restrict__ G2,
                                           const int* __restrict__ paths,
                                           const int* __restrict__ idx,
                                           const int* __restrict__ seqs, int J, int scatB,
                                           int* __restrict__ pt,
                                           const float* __restrict__ M,
                                           unsigned short* __restrict__ Mf) {
    if (blockIdx.x >= 1024) {
        int tb = blockIdx.x - 1024;
        if (tb < scatB) {
            int j = tb * 256 + threadIdx.x;
            if (j < J) pt[idx[j] * L_ + seqs[j]] = paths[j];
        } else if (tb < scatB + 8) {
            wf16(M, Mf, (tb - scatB) * 256 + threadIdx.x, 128);
        } else {
            // sentinel rows: padded steps read x = 0 -> G2 = biases only
            for (int i = threadIdx.x; i < 2048; i += 256) {
                int bx = i >> 7, cc = i & 127;
                size_t base = ((size_t)(bx * (E_ + 1) + E_) * 128 + cc) * 4;
                G2[base]     = f2h(b_in[cc] + b_rec[cc]);
                G2[base + 1] = f2h(b_in[128 + cc] + b_rec[128 + cc]);
                G2[base + 2] = f2h(b_in[256 + cc]);
                G2[base + 3] = 0;
            }
        }
        return;
    }
    __shared__ __align__(16) unsigned short a_lds[16][136];
    int tid = threadIdx.x, w = tid >> 6, L = tid & 63;
    int l15 = L & 15, q = L >> 4;
    int row0 = blockIdx.x * 16;
    int badd = row0 >> 10;              // batch index; store row = input row + badd
    {
        int r = tid >> 4, c = (tid & 15) * 8;
        const float4* p = (const float4*)(inputs + (size_t)(row0 + r) * 128 + c);
        float4 v0 = p[0], v1 = p[1];
        uint4 st;
        st.x = pk2(v0.x, v0.y); st.y = pk2(v0.z, v0.w);
        st.z = pk2(v1.x, v1.y); st.w = pk2(v1.z, v1.w);
        *(uint4*)&a_lds[r][c] = st;
    }
    __syncthreads();
    f16x8 af[4];
#pragma unroll
    for (int kt = 0; kt < 4; ++kt)
        af[kt] = *(const f16x8*)&a_lds[l15][kt * 32 + q * 8];
#pragma unroll
    for (int ct = 0; ct < 6; ++ct) {
        int tl = 6 * w + ct;
        f32x4 acc = (f32x4){0.f, 0.f, 0.f, 0.f};
#pragma unroll
        for (int kt = 0; kt < 4; ++kt)
            acc = __builtin_amdgcn_mfma_f32_16x16x32_f16(
                af[kt], *(const f16x8*)(WfI + (size_t)((tl * 4 + kt) * 64 + L) * 8), acc, 0, 0, 0);
        int g  = tl >> 3;               // 0=z, 1=r, 2=h
        int dd = (tl & 7) * 16 + l15;   // gate col 0..127
        float bia = b_in[tl * 16 + l15] + (g < 2 ? b_rec[tl * 16 + l15] : 0.f);
#pragma unroll
        for (int j = 0; j < 4; ++j) {
            int r = q * 4 + j;
            G2[((size_t)(row0 + r + badd) * 128 + dd) * 4 + g] = f2h(acc[j] + bia);
        }
    }
}

// ---- fused GRU + attention, transposed MFMA: lane owns 1 seq x 4 cols -----
// 512 thr / 8 waves, 16 seqs. Wave w: gate cols [16w,16w+16), A-tiles {w,8+w,16+w}.
// Lane (q,l15): seq l15, cols c0..c0+3 (c0 = 16w + 4q) — matches D layout of
// D = (W^T)(h^T) where both operands use the same fragment swizzle.
__global__ __launch_bounds__(512, 4) void k_rec(const unsigned short* __restrict__ WfR,
                                                const float* __restrict__ b_rec,
                                                const unsigned short* __restrict__ G2,
                                                const int* __restrict__ pt,
                                                const unsigned short* __restrict__ Mf,
                                                const unsigned short* __restrict__ wvf,
                                                float* __restrict__ out) {
    __shared__ __align__(16) unsigned short hsl[16][16][136];   // [t][seq][dim] 69632 B
    __shared__ __align__(16) unsigned short qkb[16][136];
    __shared__ __align__(16) unsigned short svb[16][136];
    __shared__ float attl[16][20];
    __shared__ int ofs_lds[16][16];                             // byte offsets into G2

    int tid = threadIdx.x, w = tid >> 6, L = tid & 63;
    int l15 = L & 15, q = L >> 4;
    int c0 = 16 * w + 4 * q;
    int n0 = blockIdx.x * 16;
    int b  = n0 >> 11;
    int p0 = n0 & (P_ - 1);
    int bb = b * (E_ + 1);

    // A-operand fragments: W^T tiles {w (z), 8+w (r), 16+w (h)}
    f16x8 afw[3][4];
#pragma unroll
    for (int g = 0; g < 3; ++g)
#pragma unroll
        for (int kt = 0; kt < 4; ++kt)
            afw[g][kt] = *(const f16x8*)(WfR + (size_t)(((g * 8 + w) * 4 + kt) * 64 + L) * 8);

    if (tid < 256)
        ofs_lds[tid >> 4][tid & 15] = (bb + pt[p0 * L_ + tid]) << 10;

    f32x4 rh4;
#pragma unroll
    for (int j = 0; j < 4; ++j) rh4[j] = b_rec[256 + c0 + j];
    float h_reg[4] = {0.f, 0.f, 0.f, 0.f};
    __syncthreads();

    const char* g2c = (const char*)G2 + (size_t)c0 * 8;
    uint4 cur0, cur1;
    {
        int off = ofs_lds[l15][0];
        cur0 = *(const uint4*)(g2c + off);
        cur1 = *(const uint4*)(g2c + off + 16);
    }

    for (int t = 0; t < L_; ++t) {
        uint4 nx0 = cur0, nx1 = cur1;
        if (t < 15) {
            int off = ofs_lds[l15][t + 1];
            nx0 = *(const uint4*)(g2c + off);
            nx1 = *(const uint4*)(g2c + off + 16);
        }

        // acc init = x-gate values (+ folded biases); MFMA adds W·h
        float xh[4];
        f32x4 acc[3];
        acc[0][0] = lo16(cur0.x); acc[0][1] = lo16(cur0.z);
        acc[0][2] = lo16(cur1.x); acc[0][3] = lo16(cur1.z);
        acc[1][0] = hi16(cur0.x); acc[1][1] = hi16(cur0.z);
        acc[1][2] = hi16(cur1.x); acc[1][3] = hi16(cur1.z);
        xh[0] = lo16(cur0.y); xh[1] = lo16(cur0.w);
        xh[2] = lo16(cur1.y); xh[3] = lo16(cur1.w);
        acc[2] = rh4;

        if (t > 0) {
            f16x8 hf[4];
#pragma unroll
            for (int kt = 0; kt < 4; ++kt)
                hf[kt] = *(const f16x8*)&hsl[t - 1][l15][kt * 32 + q * 8];
#pragma unroll
            for (int g = 0; g < 3; ++g)
#pragma unroll
                for (int kt = 0; kt < 4; ++kt)
                    acc[g] = __builtin_amdgcn_mfma_f32_16x16x32_f16(afw[g][kt], hf[kt], acc[g], 0, 0, 0);
        }

        float hn[4];
#pragma unroll
        for (int j = 0; j < 4; ++j) {
            float z   = __builtin_amdgcn_rcpf(1.f + __expf(-acc[0][j]));
            float rg  = __builtin_amdgcn_rcpf(1.f + __expf(-acc[1][j]));
            float pre = xh[j] + rg * acc[2][j];
            float hc  = 1.f - 2.f * __builtin_amdgcn_rcpf(__expf(2.f * pre) + 1.f);
            hn[j] = hc + z * (h_reg[j] - hc);
            h_reg[j] = hn[j];
        }
        uint2 st;
        st.x = pk2(hn[0], hn[1]); st.y = pk2(hn[2], hn[3]);
        *(uint2*)&hsl[t][l15][c0] = st;
        cur0 = nx0; cur1 = nx1;
        __syncthreads();
    }

    // ===== attention =====
    // qk^T = (M^T)(last^T): lane -> seq l15, cols c0..c0+3
    {
        f16x8 hf[4];
#pragma unroll
        for (int kt = 0; kt < 4; ++kt)
            hf[kt] = *(const f16x8*)&hsl[15][l15][kt * 32 + q * 8];
        f32x4 a = (f32x4){0.f, 0.f, 0.f, 0.f};
#pragma unroll
        for (int kt = 0; kt < 4; ++kt)
            a = __builtin_amdgcn_mfma_f32_16x16x32_f16(
                *(const f16x8*)(Mf + (size_t)((w * 4 + kt) * 64 + L) * 8), hf[kt], a, 0, 0, 0);
        uint2 st;
        st.x = pk2(a[0], a[1]); st.y = pk2(a[2], a[3]);
        *(uint2*)&qkb[l15][c0] = st;
    }
    __syncthreads();

    // att[s][l] = hs[s][l][:] . qk[s][:]
    if (tid < 256) {
        int s = tid & 15, l = tid >> 4;
        const uint4* hr = (const uint4*)&hsl[l][s][0];
        const uint4* qr = (const uint4*)&qkb[s][0];
        float a = 0.f;
#pragma unroll
        for (int k8 = 0; k8 < 16; ++k8) {
            uint4 hh = hr[k8], qq = qr[k8];
            a = dot2w(hh.x, qq.x, a); a = dot2w(hh.y, qq.y, a);
            a = dot2w(hh.z, qq.z, a); a = dot2w(hh.w, qq.w, a);
        }
        attl[s][l] = a;
    }
    __syncthreads();

    // svec[s][d] = sum_l att[s][l] * hs[s][l][d]
    {
        int s = tid >> 5, d0 = (tid & 31) * 4;
        float v[4] = {0.f, 0.f, 0.f, 0.f};
#pragma unroll
        for (int l = 0; l < 16; ++l) {
            float a = attl[s][l];
            uint2 hu = *(const uint2*)&hsl[l][s][d0];
            v[0] += a * lo16(hu.x); v[1] += a * hi16(hu.x);
            v[2] += a * lo16(hu.y); v[3] += a * hi16(hu.y);
        }
        uint2 st;
        st.x = pk2(v[0], v[1]); st.y = pk2(v[2], v[3]);
        *(uint2*)&svb[s][d0] = st;
    }
    __syncthreads();

    // ctx^T = (wv^T)(svec^T) -> out[seq][c0..c0+3] as one dwordx4
    {
        f16x8 sf[4];
#pragma unroll
        for (int kt = 0; kt < 4; ++kt)
            sf[kt] = *(const f16x8*)&svb[l15][kt * 32 + q * 8];
        f32x4 a = (f32x4){0.f, 0.f, 0.f, 0.f};
#pragma unroll
        for (int kt = 0; kt < 4; ++kt)
            a = __builtin_amdgcn_mfma_f32_16x16x32_f16(
                *(const f16x8*)(wvf + (size_t)((w * 4 + kt) * 64 + L) * 8), sf[kt], a, 0, 0, 0);
        *(f32x4*)&out[(size_t)(n0 + l15) * D_ + c0] = a;
    }
}

// ---------------------------------------------------------------------------
extern "C" void kernel_launch(void* const* d_in, const int* in_sizes, int n_in,
                              void* d_out, int out_size, void* d_ws, size_t ws_size,
                              hipStream_t stream) {
    const float* inputs = (const float*)d_in[0];
    const float* W_in   = (const float*)d_in[1];
    const float* W_rec  = (const float*)d_in[2];
    const float* b_in   = (const float*)d_in[3];
    const float* b_rec  = (const float*)d_in[4];
    const float* wq     = (const float*)d_in[5];
    const float* wk     = (const float*)d_in[6];
    const float* wvp    = (const float*)d_in[7];
    const int* paths    = (const int*)d_in[8];
    const int* idx      = (const int*)d_in[9];
    const int* seqs     = (const int*)d_in[10];
    int J = in_sizes[8];

    // ws layout (bytes): total ~17.25 MiB
    const size_t off_pt  = 0;
    const size_t off_WfR = off_pt  + (size_t)P_ * L_ * 4;        // 131072
    const size_t off_WfI = off_WfR + (size_t)24 * 256 * 16;      // +98304
    const size_t off_Mf  = off_WfI + (size_t)24 * 256 * 16;      // +98304
    const size_t off_wvf = off_Mf  + (size_t)8 * 256 * 16;       // +32768
    const size_t off_M   = off_wvf + (size_t)8 * 256 * 16;       // +32768
    const size_t off_G2  = off_M   + (size_t)128 * 128 * 4;      // +65536
    // G2: 16 * 1025 * 128 * 4 u16 = 16,793,600 B
    char* ws = (char*)d_ws;
    int* pt             = (int*)(ws + off_pt);
    unsigned short* WfR = (unsigned short*)(ws + off_WfR);
    unsigned short* WfI = (unsigned short*)(ws + off_WfI);
    unsigned short* Mf  = (unsigned short*)(ws + off_Mf);
    unsigned short* wvf = (unsigned short*)(ws + off_wvf);
    float* M            = (float*)(ws + off_M);
    unsigned short* G2  = (unsigned short*)(ws + off_G2);
    float* out = (float*)d_out;

    int scatB = (J + 255) / 256;
    k_prep<<<dim3(248), dim3(256), 0, stream>>>(W_rec, W_in, wq, wk, wvp, pt,
                                                WfR, WfI, wvf, M);
    k_G<<<dim3(1024 + scatB + 8 + 1), dim3(256), 0, stream>>>(inputs, WfI, b_in, b_rec,
                                                              G2, paths, idx, seqs, J,
                                                              scatB, pt, M, Mf);
    k_rec<<<dim3(B_ * P_ / 16), dim3(512), 0, stream>>>(WfR, b_rec, G2, pt,
                                                        Mf, wvf, out);
}

// Round 10
// 179.082 us; speedup vs baseline: 7.1858x; 1.0394x over previous
//
#include <hip/hip_runtime.h>
#include <hip/hip_bf16.h>
#include <cstddef>

#define P_ 2048
#define B_ 16
#define E_ 1024
#define D_ 128
#define L_ 16
#define TD_ 384

typedef _Float16 f16x2 __attribute__((ext_vector_type(2)));
typedef _Float16 f16x8 __attribute__((ext_vector_type(8)));
typedef float    f32x4 __attribute__((ext_vector_type(4)));

__device__ __forceinline__ unsigned short f2h(float x) {
    _Float16 h = (_Float16)x;
    return __builtin_bit_cast(unsigned short, h);
}
__device__ __forceinline__ unsigned pk2(float a, float b) {
    return __builtin_bit_cast(unsigned, __builtin_amdgcn_cvt_pkrtz(a, b));
}
__device__ __forceinline__ float lo16(unsigned u) {
    return (float)__builtin_bit_cast(f16x2, u)[0];
}
__device__ __forceinline__ float hi16(unsigned u) {
    return (float)__builtin_bit_cast(f16x2, u)[1];
}
__device__ __forceinline__ float dot2w(unsigned hu, unsigned qu, float c) {
#if __has_builtin(__builtin_amdgcn_fdot2)
    typedef __fp16 h2v __attribute__((ext_vector_type(2)));
    return __builtin_amdgcn_fdot2(__builtin_bit_cast(h2v, hu),
                                  __builtin_bit_cast(h2v, qu), c, false);
#else
    f16x2 h = __builtin_bit_cast(f16x2, hu), q = __builtin_bit_cast(f16x2, qu);
    return c + (float)h[0] * (float)q[0] + (float)h[1] * (float)q[1];
#endif
}

// ---- fragment swizzle (f16): frag[(tile*4+kt)*64+lane][j] = src[k0+j][tile*16+(lane&15)]
// Works as MFMA B-operand (B[k][n]) AND as A-operand (A[m][k] = src^T[m][k]).
__device__ __forceinline__ void wf16(const float* __restrict__ src,
                                     unsigned short* __restrict__ dst, int g, int N) {
    int lane = g & 63, kt = (g >> 6) & 3, tile = g >> 8;
    int k0 = kt * 32 + (lane >> 4) * 8;
    int c = tile * 16 + (lane & 15);
#pragma unroll
    for (int j = 0; j < 8; ++j)
        dst[(size_t)g * 8 + j] = f2h(src[(size_t)(k0 + j) * N + c]);
}

// ---- k_prep: pt init (to sentinel E_) + weight swizzles + M = wq@wk^T -----
// blocks: [0,128) pt | [128,152) WfR | [152,176) WfI | [176,184) wvf | [184,248) M
__global__ __launch_bounds__(256) void k_prep(const float* __restrict__ W_rec,
                                              const float* __restrict__ W_in,
                                              const float* __restrict__ wq,
                                              const float* __restrict__ wk,
                                              const float* __restrict__ wv,
                                              int* __restrict__ pt,
                                              unsigned short* __restrict__ WfR,
                                              unsigned short* __restrict__ WfI,
                                              unsigned short* __restrict__ wvf,
                                              float* __restrict__ M) {
    __shared__ float wk_lds[128 * 129];
    __shared__ float wq_row2[2][128];
    int blk = blockIdx.x, tid = threadIdx.x;
    if      (blk < 128) { pt[blk * 256 + tid] = E_; return; }
    else if (blk < 152) { wf16(W_rec, WfR, (blk - 128) * 256 + tid, TD_); return; }
    else if (blk < 176) { wf16(W_in,  WfI, (blk - 152) * 256 + tid, TD_); return; }
    else if (blk < 184) { wf16(wv,    wvf, (blk - 176) * 256 + tid, 128); return; }
    int j0 = (blk - 184) * 2;
    int d = tid & 127, half = tid >> 7;
    for (int r = half * 64; r < half * 64 + 64; ++r)
        wk_lds[r * 129 + d] = wk[r * 128 + d];
    wq_row2[half][d] = wq[(j0 + half) * 128 + d];
    __syncthreads();
    float acc = 0.f;
    for (int k = 0; k < 128; ++k) acc += wq_row2[half][k] * wk_lds[d * 129 + k];
    M[(j0 + half) * 128 + d] = acc;
}

// ---- k_G: G2[b*1025+e][col][4]={z+bz+rz, r+br+rr, xh+bh, pad} (f16) -------
// tails: pt scatter + Mf swizzle + sentinel rows (pure-bias)
__global__ __launch_bounds__(256) void k_G(const float* __restrict__ inputs,
                                           const unsigned short* __restrict__ WfI,
                                           const float* __restrict__ b_in,
                                           const float* __restrict__ b_rec,
                                           unsigned short* __restrict__ G2,
                                           const int* __restrict__ paths,
                                           const int* __restrict__ idx,
                                           const int* __restrict__ seqs, int J, int scatB,
                                           int* __restrict__ pt,
                                           const float* __restrict__ M,
                                           unsigned short* __restrict__ Mf) {
    if (blockIdx.x >= 1024) {
        int tb = blockIdx.x - 1024;
        if (tb < scatB) {
            int j = tb * 256 + threadIdx.x;
            if (j < J) pt[idx[j] * L_ + seqs[j]] = paths[j];
        } else if (tb < scatB + 8) {
            wf16(M, Mf, (tb - scatB) * 256 + threadIdx.x, 128);
        } else {
            // sentinel rows: padded steps read x = 0 -> G2 = biases only
            for (int i = threadIdx.x; i < 2048; i += 256) {
                int bx = i >> 7, cc = i & 127;
                size_t base = ((size_t)(bx * (E_ + 1) + E_) * 128 + cc) * 4;
                G2[base]     = f2h(b_in[cc] + b_rec[cc]);
                G2[base + 1] = f2h(b_in[128 + cc] + b_rec[128 + cc]);
                G2[base + 2] = f2h(b_in[256 + cc]);
                G2[base + 3] = 0;
            }
        }
        return;
    }
    __shared__ __align__(16) unsigned short a_lds[16][136];
    int tid = threadIdx.x, w = tid >> 6, L = tid & 63;
    int l15 = L & 15, q = L >> 4;
    int row0 = blockIdx.x * 16;
    int badd = row0 >> 10;              // batch index; store row = input row + badd
    {
        int r = tid >> 4, c = (tid & 15) * 8;
        const float4* p = (const float4*)(inputs + (size_t)(row0 + r) * 128 + c);
        float4 v0 = p[0], v1 = p[1];
        uint4 st;
        st.x = pk2(v0.x, v0.y); st.y = pk2(v0.z, v0.w);
        st.z = pk2(v1.x, v1.y); st.w = pk2(v1.z, v1.w);
        *(uint4*)&a_lds[r][c] = st;
    }
    __syncthreads();
    f16x8 af[4];
#pragma unroll
    for (int kt = 0; kt < 4; ++kt)
        af[kt] = *(const f16x8*)&a_lds[l15][kt * 32 + q * 8];
#pragma unroll
    for (int ct = 0; ct < 6; ++ct) {
        int tl = 6 * w + ct;
        f32x4 acc = (f32x4){0.f, 0.f, 0.f, 0.f};
#pragma unroll
        for (int kt = 0; kt < 4; ++kt)
            acc = __builtin_amdgcn_mfma_f32_16x16x32_f16(
                af[kt], *(const f16x8*)(WfI + (size_t)((tl * 4 + kt) * 64 + L) * 8), acc, 0, 0, 0);
        int g  = tl >> 3;               // 0=z, 1=r, 2=h
        int dd = (tl & 7) * 16 + l15;   // gate col 0..127
        float bia = b_in[tl * 16 + l15] + (g < 2 ? b_rec[tl * 16 + l15] : 0.f);
#pragma unroll
        for (int j = 0; j < 4; ++j) {
            int r = q * 4 + j;
            G2[((size_t)(row0 + r + badd) * 128 + dd) * 4 + g] = f2h(acc[j] + bia);
        }
    }
}

// ---- fused GRU + attention, transposed MFMA: lane owns 1 seq x 4 cols -----
// 512 thr / 8 waves, 16 seqs. Wave w: gate cols [16w,16w+16), A-tiles {w,8+w,16+w}.
// Lane (q,l15): seq l15, cols c0..c0+3 (c0 = 16w + 4q).
__global__ __launch_bounds__(512, 4) void k_rec(const unsigned short* __restrict__ WfR,
                                                const float* __restrict__ b_rec,
                                                const unsigned short* __restrict__ G2,
                                                const int* __restrict__ pt,
                                                const unsigned short* __restrict__ Mf,
                                                const unsigned short* __restrict__ wvf,
                                                float* __restrict__ out) {
    __shared__ __align__(16) unsigned short hsl[16][16][136];   // [t][seq][dim] 69632 B
    __shared__ __align__(16) unsigned short qkb[16][136];       // 4352 B
    __shared__ __align__(16) unsigned short svb[16][136];       // 4352 B
    __shared__ float attp[2][16][16];                           // 2048 B
    __shared__ int ofs_lds[16][16];                             // 1024 B  (total 81408)

    int tid = threadIdx.x, w = tid >> 6, L = tid & 63;
    int l15 = L & 15, q = L >> 4;
    int c0 = 16 * w + 4 * q;
    int n0 = blockIdx.x * 16;
    int b  = n0 >> 11;
    int p0 = n0 & (P_ - 1);
    int bb = b * (E_ + 1);

    // A-operand fragments: W^T tiles {w (z), 8+w (r), 16+w (h)}
    f16x8 afw[3][4];
#pragma unroll
    for (int g = 0; g < 3; ++g)
#pragma unroll
        for (int kt = 0; kt < 4; ++kt)
            afw[g][kt] = *(const f16x8*)(WfR + (size_t)(((g * 8 + w) * 4 + kt) * 64 + L) * 8);

    if (tid < 256)
        ofs_lds[tid >> 4][tid & 15] = (bb + pt[p0 * L_ + tid]) << 10;

    f32x4 rh4;
#pragma unroll
    for (int j = 0; j < 4; ++j) rh4[j] = b_rec[256 + c0 + j];
    float h_reg[4] = {0.f, 0.f, 0.f, 0.f};
    __syncthreads();

    // preload all 16 step-offsets for my seq into registers
    int ofs[16];
    {
        const uint4* op = (const uint4*)&ofs_lds[l15][0];
        uint4 o0 = op[0], o1 = op[1], o2 = op[2], o3 = op[3];
        ofs[0]  = o0.x; ofs[1]  = o0.y; ofs[2]  = o0.z; ofs[3]  = o0.w;
        ofs[4]  = o1.x; ofs[5]  = o1.y; ofs[6]  = o1.z; ofs[7]  = o1.w;
        ofs[8]  = o2.x; ofs[9]  = o2.y; ofs[10] = o2.z; ofs[11] = o2.w;
        ofs[12] = o3.x; ofs[13] = o3.y; ofs[14] = o3.z; ofs[15] = o3.w;
    }

    const char* g2c = (const char*)G2 + (size_t)c0 * 8;
    uint4 cur0 = *(const uint4*)(g2c + ofs[0]);
    uint4 cur1 = *(const uint4*)(g2c + ofs[0] + 16);

#pragma unroll
    for (int t = 0; t < L_; ++t) {
        uint4 nx0 = cur0, nx1 = cur1;
        if (t < 15) {
            const char* gp = g2c + ofs[t + 1];
            nx0 = *(const uint4*)(gp);
            nx1 = *(const uint4*)(gp + 16);
        }

        // acc init = x-gate values (+ folded biases); MFMA adds W·h
        float xh[4];
        f32x4 acc[3];
        acc[0][0] = lo16(cur0.x); acc[0][1] = lo16(cur0.z);
        acc[0][2] = lo16(cur1.x); acc[0][3] = lo16(cur1.z);
        acc[1][0] = hi16(cur0.x); acc[1][1] = hi16(cur0.z);
        acc[1][2] = hi16(cur1.x); acc[1][3] = hi16(cur1.z);
        xh[0] = lo16(cur0.y); xh[1] = lo16(cur0.w);
        xh[2] = lo16(cur1.y); xh[3] = lo16(cur1.w);
        acc[2] = rh4;

        if (t > 0) {
            f16x8 hf[4];
#pragma unroll
            for (int kt = 0; kt < 4; ++kt)
                hf[kt] = *(const f16x8*)&hsl[t - 1][l15][kt * 32 + q * 8];
#pragma unroll
            for (int g = 0; g < 3; ++g)
#pragma unroll
                for (int kt = 0; kt < 4; ++kt)
                    acc[g] = __builtin_amdgcn_mfma_f32_16x16x32_f16(afw[g][kt], hf[kt], acc[g], 0, 0, 0);
        }

        float hn[4];
#pragma unroll
        for (int j = 0; j < 4; ++j) {
            float z   = __builtin_amdgcn_rcpf(1.f + __expf(-acc[0][j]));
            float rg  = __builtin_amdgcn_rcpf(1.f + __expf(-acc[1][j]));
            float pre = xh[j] + rg * acc[2][j];
            float hc  = 1.f - 2.f * __builtin_amdgcn_rcpf(__expf(2.f * pre) + 1.f);
            hn[j] = hc + z * (h_reg[j] - hc);
            h_reg[j] = hn[j];
        }
        uint2 st;
        st.x = pk2(hn[0], hn[1]); st.y = pk2(hn[2], hn[3]);
        *(uint2*)&hsl[t][l15][c0] = st;
        cur0 = nx0; cur1 = nx1;

        // light barrier: drain LDS only (lgkmcnt(0)); leave G2 prefetch (vmcnt) in flight
        __builtin_amdgcn_wave_barrier();
        __builtin_amdgcn_s_waitcnt(0xC07F);
        __builtin_amdgcn_s_barrier();
        __builtin_amdgcn_wave_barrier();
    }

    // ===== attention =====
    // qk^T = (M^T)(last^T): lane -> seq l15, cols c0..c0+3
    {
        f16x8 hf[4];
#pragma unroll
        for (int kt = 0; kt < 4; ++kt)
            hf[kt] = *(const f16x8*)&hsl[15][l15][kt * 32 + q * 8];
        f32x4 a = (f32x4){0.f, 0.f, 0.f, 0.f};
#pragma unroll
        for (int kt = 0; kt < 4; ++kt)
            a = __builtin_amdgcn_mfma_f32_16x16x32_f16(
                *(const f16x8*)(Mf + (size_t)((w * 4 + kt) * 64 + L) * 8), hf[kt], a, 0, 0, 0);
        uint2 st;
        st.x = pk2(a[0], a[1]); st.y = pk2(a[2], a[3]);
        *(uint2*)&qkb[l15][c0] = st;
    }
    __syncthreads();

    // att partials: all 512 threads; half = k-range [0,64) or [64,128)
    {
        int s = tid & 15, l = (tid >> 4) & 15, half = tid >> 8;
        const uint4* hr = (const uint4*)&hsl[l][s][half * 64];
        const uint4* qr = (const uint4*)&qkb[s][half * 64];
        float a = 0.f;
#pragma unroll
        for (int k8 = 0; k8 < 8; ++k8) {
            uint4 hh = hr[k8], qq = qr[k8];
            a = dot2w(hh.x, qq.x, a); a = dot2w(hh.y, qq.y, a);
            a = dot2w(hh.z, qq.z, a); a = dot2w(hh.w, qq.w, a);
        }
        attp[half][s][l] = a;
    }
    __syncthreads();

    // svec[s][d] = sum_l att[s][l] * hs[s][l][d]
    {
        int s = tid >> 5, d0 = (tid & 31) * 4;
        float v[4] = {0.f, 0.f, 0.f, 0.f};
#pragma unroll
        for (int l = 0; l < 16; ++l) {
            float a = attp[0][s][l] + attp[1][s][l];
            uint2 hu = *(const uint2*)&hsl[l][s][d0];
            v[0] += a * lo16(hu.x); v[1] += a * hi16(hu.x);
            v[2] += a * lo16(hu.y); v[3] += a * hi16(hu.y);
        }
        uint2 st;
        st.x = pk2(v[0], v[1]); st.y = pk2(v[2], v[3]);
        *(uint2*)&svb[s][d0] = st;
    }
    __syncthreads();

    // ctx^T = (wv^T)(svec^T) -> out[seq][c0..c0+3] as one dwordx4
    {
        f16x8 sf[4];
#pragma unroll
        for (int kt = 0; kt < 4; ++kt)
            sf[kt] = *(const f16x8*)&svb[l15][kt * 32 + q * 8];
        f32x4 a = (f32x4){0.f, 0.f, 0.f, 0.f};
#pragma unroll
        for (int kt = 0; kt < 4; ++kt)
            a = __builtin_amdgcn_mfma_f32_16x16x32_f16(
                *(const f16x8*)(wvf + (size_t)((w * 4 + kt) * 64 + L) * 8), sf[kt], a, 0, 0, 0);
        *(f32x4*)&out[(size_t)(n0 + l15) * D_ + c0] = a;
    }
}

// ---------------------------------------------------------------------------
extern "C" void kernel_launch(void* const* d_in, const int* in_sizes, int n_in,
                              void* d_out, int out_size, void* d_ws, size_t ws_size,
                              hipStream_t stream) {
    const float* inputs = (const float*)d_in[0];
    const float* W_in   = (const float*)d_in[1];
    const float* W_rec  = (const float*)d_in[2];
    const float* b_in   = (const float*)d_in[3];
    const float* b_rec  = (const float*)d_in[4];
    const float* wq     = (const float*)d_in[5];
    const float* wk     = (const float*)d_in[6];
    const float* wvp    = (const float*)d_in[7];
    const int* paths    = (const int*)d_in[8];
    const int* idx      = (const int*)d_in[9];
    const int* seqs     = (const int*)d_in[10];
    int J = in_sizes[8];

    // ws layout (bytes): total ~17.25 MiB
    const size_t off_pt  = 0;
    const size_t off_WfR = off_pt  + (size_t)P_ * L_ * 4;        // 131072
    const size_t off_WfI = off_WfR + (size_t)24 * 256 * 16;      // +98304
    const size_t off_Mf  = off_WfI + (size_t)24 * 256 * 16;      // +98304
    const size_t off_wvf = off_Mf  + (size_t)8 * 256 * 16;       // +32768
    const size_t off_M   = off_wvf + (size_t)8 * 256 * 16;       // +32768
    const size_t off_G2  = off_M   + (size_t)128 * 128 * 4;      // +65536
    // G2: 16 * 1025 * 128 * 4 u16 = 16,793,600 B
    char* ws = (char*)d_ws;
    int* pt             = (int*)(ws + off_pt);
    unsigned short* WfR = (unsigned short*)(ws + off_WfR);
    unsigned short* WfI = (unsigned short*)(ws + off_WfI);
    unsigned short* Mf  = (unsigned short*)(ws + off_Mf);
    unsigned short* wvf = (unsigned short*)(ws + off_wvf);
    float* M            = (float*)(ws + off_M);
    unsigned short* G2  = (unsigned short*)(ws + off_G2);
    float* out = (float*)d_out;

    int scatB = (J + 255) / 256;
    k_prep<<<dim3(248), dim3(256), 0, stream>>>(W_rec, W_in, wq, wk, wvp, pt,
                                                WfR, WfI, wvf, M);
    k_G<<<dim3(1024 + scatB + 8 + 1), dim3(256), 0, stream>>>(inputs, WfI, b_in, b_rec,
                                                              G2, paths, idx, seqs, J,
                                                              scatB, pt, M, Mf);
    k_rec<<<dim3(B_ * P_ / 16), dim3(512), 0, stream>>>(WfR, b_rec, G2, pt,
                                                        Mf, wvf, out);
}